// Round 10
// baseline (831.256 us; speedup 1.0000x reference)
//
#include <hip/hip_runtime.h>
#include <hip/hip_bf16.h>
#include <math.h>

#define B_ 32
#define S_ 60
#define T_ 48
#define H_ 512
#define E_ 512
#define V_ 50257
#define NPAD 50432   // V_ padded up to multiple of 256
#define EPI_LD 260   // padded LDS stride for epilogue staging
#define NCOL (NPAD / 256)           // 197 output column blocks

typedef __attribute__((ext_vector_type(8))) short bf16x8v;
typedef __attribute__((ext_vector_type(4))) float f32x4v;
typedef __attribute__((ext_vector_type(4))) float f32x4a __attribute__((aligned(4)));
typedef __attribute__((ext_vector_type(4))) unsigned int u32x4;

__device__ inline unsigned short f2bf(float f) {
    union { float f; unsigned u; } v; v.f = f;
    unsigned r = v.u + 0x7fffu + ((v.u >> 16) & 1u);   // round-to-nearest-even
    return (unsigned short)(r >> 16);
}
__device__ inline float bflo(unsigned u) { return __uint_as_float(u << 16); }

__device__ inline void gload_lds16(const void* g, void* l) {
    __builtin_amdgcn_global_load_lds(
        (const __attribute__((address_space(1))) unsigned int*)g,
        (__attribute__((address_space(3))) unsigned int*)l, 16, 0, 0);
}

// ---------------------------------------------------------------------------
// LLC-coherent (cache-bypassing) access helpers. sc0+sc1 => read/write at the
// coherence point. Rules (r4/r7 post-mortems):
//  - cells READ by other blocks in-flight (flags, sG, ctxG, xG*) are touched
//    ONLY via sc0sc1 on both sides;
//  - write-once buffers (Wt, dec_b, energy, pre) are WRITTEN sc0sc1
//    (write-through, no dirty L2 copies) and may be READ PLAIN after a
//    ready-gate (values are iteration-invariant, so even cached clean
//    copies from prior launches are correct).
// ---------------------------------------------------------------------------
__device__ __forceinline__ float ld_coh_f32_nw(const float* p) {   // no wait
    float r;
    asm volatile("global_load_dword %0, %1, off sc0 sc1"
                 : "=v"(r) : "v"(p) : "memory");
    return r;
}
__device__ __forceinline__ void st_coh_f32(float* p, float v) {
    asm volatile("global_store_dword %0, %1, off sc0 sc1"
                 :: "v"(p), "v"(v) : "memory");
}
__device__ __forceinline__ void st_coh_u16(unsigned short* p, unsigned int v) {
    asm volatile("global_store_short %0, %1, off sc0 sc1"
                 :: "v"(p), "v"(v) : "memory");
}
__device__ __forceinline__ void st_coh_u32(int* p, int v) {
    asm volatile("global_store_dword %0, %1, off sc0 sc1"
                 :: "v"(p), "v"(v) : "memory");
}
__device__ __forceinline__ void st_coh_u64(unsigned long long* p, unsigned long long v) {
    asm volatile("global_store_dwordx2 %0, %1, off sc0 sc1"
                 :: "v"(p), "v"(v) : "memory");
}
__device__ __forceinline__ int ld_coh_u32(const int* p) {
    int r;
    asm volatile("global_load_dword %0, %1, off sc0 sc1\n\ts_waitcnt vmcnt(0)"
                 : "=v"(r) : "v"(p) : "memory");
    return r;
}
__device__ __forceinline__ u32x4 ld_cohx4(const void* p) {
    u32x4 r;
    asm volatile("global_load_dwordx4 %0, %1, off sc0 sc1"
                 : "=v"(r) : "v"(p) : "memory");
    return r;                     // caller must s_waitcnt vmcnt(0) before use
}

// ---------------------------------------------------------------------------
// 32-block device barrier, flag-array form.
// ---------------------------------------------------------------------------
__device__ __forceinline__ void gbar(int* flags, int idx, int bi) {
    asm volatile("s_waitcnt vmcnt(0)" ::: "memory");
    __syncthreads();
    if (threadIdx.x == 0)
        st_coh_u32(&flags[idx * 32 + bi], 1);
    if (threadIdx.x < 64) {
        const int* fp = &flags[idx * 32 + (threadIdx.x & 31)];
        for (;;) {
            int v = ld_coh_u32(fp);
            if (__all(v != 0)) break;
            __builtin_amdgcn_s_sleep(1);
        }
    }
    __syncthreads();
}

// ---------------------------------------------------------------------------
// fp32 tiled GEMM body; 256-thread TEAM (tid = team-local 0..255), 64x128
// tile, BK=8. Epilogue stores are sc0sc1 (consumed cross-block in-kernel).
// ---------------------------------------------------------------------------
template<int ACT, bool GATHER>
__device__ void gemm_team(int tid, const float* __restrict__ A,
                          const float* __restrict__ Bm,
                          const float* __restrict__ bias, float* __restrict__ C,
                          int N, int K, int lda, const int* __restrict__ gidx,
                          int cb, int rb, float (*As)[128], float (*Bs)[128])
{
    const int am = (tid & 127) >> 1;          // 0..63
    const int ak = (tid & 1) * 4;
    const bool aact = (tid < 128);
    const int arow = rb + am;
    const float* Arow;
    if (GATHER) Arow = A + (size_t)gidx[arow] * lda;
    else        Arow = A + (size_t)arow * lda;

    const int bk = tid >> 5;                  // 0..7
    const int bn = (tid & 31) * 4;

    const int tx = tid & 15, ty = tid >> 4;   // ty 0..15
    float acc[4][8];
    #pragma unroll
    for (int i = 0; i < 4; i++)
        #pragma unroll
        for (int j = 0; j < 8; j++) acc[i][j] = 0.f;

    for (int k0 = 0; k0 < K; k0 += 8) {
        float4 av, bv;
        if (aact) av = *(const float4*)(Arow + k0 + ak);
        bv = *(const float4*)(Bm + (size_t)(k0 + bk) * N + cb + bn);
        __syncthreads();
        if (aact) {
            As[ak + 0][am] = av.x; As[ak + 1][am] = av.y;
            As[ak + 2][am] = av.z; As[ak + 3][am] = av.w;
        }
        Bs[bk][bn + 0] = bv.x; Bs[bk][bn + 1] = bv.y;
        Bs[bk][bn + 2] = bv.z; Bs[bk][bn + 3] = bv.w;
        __syncthreads();

        #pragma unroll
        for (int k = 0; k < 8; k++) {
            float a[4], b[8];
            *(float4*)(a)     = *(const float4*)&As[k][ty * 4];
            *(float4*)(b)     = *(const float4*)&Bs[k][tx * 4];
            *(float4*)(b + 4) = *(const float4*)&Bs[k][tx * 4 + 64];
            #pragma unroll
            for (int i = 0; i < 4; i++)
                #pragma unroll
                for (int j = 0; j < 8; j++)
                    acc[i][j] = fmaf(a[i], b[j], acc[i][j]);
        }
    }

    #pragma unroll
    for (int i = 0; i < 4; i++) {
        int row = rb + ty * 4 + i;
        #pragma unroll
        for (int j = 0; j < 8; j++) {
            int col = cb + ((j < 4) ? (tx * 4 + j) : (64 + tx * 4 + (j - 4)));
            float v = acc[i][j] + bias[col];
            if (ACT == 1) v = tanhf(v);
            st_coh_f32(&C[(size_t)row * N + col], v);     // write-through
        }
    }
}

// ---------------------------------------------------------------------------
// LDS union: scan path / helper phases (prologue teams, transpose, gemm).
// 161792 B -> 1 block/CU everywhere.
// Flag rows in cnt: 0..95 gbar; 100 sF; 101..107 hF; 108 aggF; 110..114 pF.
// ---------------------------------------------------------------------------
union __align__(16) ScanSM {
    struct {
        float eL[S_][H_];        // 122880 B
        float part[8 * 32 * 36]; // 36864 B; overlay: sA[0..511] score[512..575] alpha[576..639]
        float sCol[512];         // 2048 B
    } s;
    struct { float As[2][8][128]; float Bs[2][8][128]; } p;  // prologue teams (16 KB)
    float til[2 * 32 * 33];      // transpose tiles
    char g[49152];               // gemm smem
};

// ---------------------------------------------------------------------------
// x exchange buffers in MFMA-FRAGMENT order (direct LLC fragment loads).
// ---------------------------------------------------------------------------
template<int LI>
__device__ __forceinline__ void highway(
    int t, int bi, int tid, int lane, int wv,
    const bf16x8v (&wf)[2][2],
    const unsigned short* __restrict__ xsrc,
    unsigned short* __restrict__ xG1,
    const float* __restrict__ ctxG,
    float* __restrict__ sG,
    unsigned short* __restrict__ dec_b,
    const float* __restrict__ pre,
    float cbh, float cbt,
    float* part, float* sCol)
{
    const int l15 = lane & 15, lc = lane >> 4;
    const int b = tid >> 4, hi = tid & 15;
    const int h = bi * 16 + hi;

    // ---- issue cross-block ctx load + pre loads early (latency hidden) ----
    float cxv = 0.f, prh = 0.f, prt = 0.f;
    if (LI == 0) {
        cxv = ld_coh_f32_nw(ctxG + (size_t)b * 512 + h);
        const float* pr = pre + ((size_t)t * B_ + b) * 1024;
        prh = pr[h]; prt = pr[h + 512];
    }

    // ---- direct per-lane fragment loads from LLC (8 x 16B per lane) ----
    u32x4 xr[2][2][2];                       // [ktl][pl][mt]
    #pragma unroll
    for (int ktl = 0; ktl < 2; ++ktl)
        #pragma unroll
        for (int pl = 0; pl < 2; ++pl)
            #pragma unroll
            for (int mt = 0; mt < 2; ++mt) {
                int ch = (((wv * 2 + ktl) * 2 + pl) * 4 + lc) * 32 + mt * 16 + l15;
                xr[ktl][pl][mt] = ld_cohx4(xsrc + (size_t)ch * 8);
            }
    asm volatile("s_waitcnt vmcnt(0)" ::: "memory");
    __builtin_amdgcn_sched_barrier(0);

    // ---- MFMA: wave wv owns k-tiles {2wv, 2wv+1} ----
    f32x4v acc[2][2];
    #pragma unroll
    for (int mt = 0; mt < 2; ++mt)
        #pragma unroll
        for (int nt = 0; nt < 2; ++nt) acc[mt][nt] = (f32x4v)0.f;

    #pragma unroll
    for (int ktl = 0; ktl < 2; ++ktl)
        #pragma unroll
        for (int pl = 0; pl < 2; ++pl)
            #pragma unroll
            for (int mt = 0; mt < 2; ++mt) {
                bf16x8v xv = *(bf16x8v*)&xr[ktl][pl][mt];
                #pragma unroll
                for (int nt = 0; nt < 2; ++nt)
                    acc[mt][nt] = __builtin_amdgcn_mfma_f32_16x16x32_bf16(
                        wf[ktl][nt], xv, acc[mt][nt], 0, 0, 0);
            }

    #pragma unroll
    for (int mt = 0; mt < 2; ++mt)
        #pragma unroll
        for (int nt = 0; nt < 2; ++nt)
            *(f32x4v*)&part[(wv * 32 + mt * 16 + l15) * 36 + nt * 16 + lc * 4] = acc[mt][nt];
    __syncthreads();

    // ---- 8-way reduce + gates; thread tid -> (b = tid>>4, hi = tid&15) ----
    float rh = 0.f, rt = 0.f;
    #pragma unroll
    for (int w = 0; w < 8; ++w) {
        rh += part[(w * 32 + b) * 36 + hi];
        rt += part[(w * 32 + b) * 36 + 16 + hi];
    }
    float ph = rh + cbh, pt = rt + cbt;
    if (LI == 0) { ph += prh; pt += prt; }
    float hh = tanhf(ph);
    float tg = 1.f / (1.f + __expf(-pt));
    float sold = sCol[tid];
    float sn = hh * tg + sold * (1.f - tg);
    sCol[tid] = sn;
    if (LI == 0) {
        float x1 = sn * cxv;
        unsigned short xh = f2bf(x1);
        unsigned short xl = f2bf(x1 - bflo((unsigned)xh));
        int kt = h >> 5, lc2 = (h >> 3) & 3, jj = h & 7;
        int ch = (kt * 8 + lc2) * 32 + b;
        st_coh_u16(xG1 + (size_t)ch * 8 + jj, xh);
        st_coh_u16(xG1 + (size_t)(ch + 128) * 8 + jj, xl);
    } else {
        st_coh_f32(sG + ((size_t)bi * 32 + b) * 16 + hi, sn);
        st_coh_u16(dec_b + ((size_t)bi * 1536 + (size_t)t * B_ + b) * 16 + hi,
                   f2bf(sn));
    }
}

// ---------------------------------------------------------------------------
// SINGLE fused kernel:
//   blocks 0..31   = cooperative scan (gated on prologue pF flags);
//                    block 0 publishes the aggregated epoch aggF.
//   blocks 32..187 = phase 0: TWO 256-thread teams, one prologue tile each
//                    (blocks 32..91 energy 64x128, 92..187 pre 64x128),
//                    publish pF -> phase 1 transpose -> hF barrier ->
//                    phase 2 column-major output GEMM (helper ci owns column
//                    block ci for all 12 row blocks, gated on aggF).
//   blocks 188..255= transpose + GEMM only (ci >= 197 idle in phase 2 tail).
// Dependency graph: scan <- pF (unconditional); GEMM <- aggF (scan publishes
// unconditionally); hF is helper-only. Acyclic -> no deadlock.
// ---------------------------------------------------------------------------
__global__ __launch_bounds__(512, 2)
void scan_tr(const float* __restrict__ enc_h, const float* __restrict__ attn_W,
             const float* __restrict__ attn_b, float* __restrict__ energy,
             const float* __restrict__ embed_W, const float* __restrict__ inp_W,
             const float* __restrict__ inp_b, float* __restrict__ pre,
             const int* __restrict__ target,
             const float* __restrict__ prev_s,
             const float* __restrict__ cell_W, const float* __restrict__ cell_b,
             unsigned short* __restrict__ dec_b,
             const float* __restrict__ outW, unsigned short* __restrict__ Wt,
             float* __restrict__ ctxG, float* __restrict__ sG,
             unsigned short* __restrict__ xG0, unsigned short* __restrict__ xG1,
             int* __restrict__ cnt,
             const float* __restrict__ out_b, float* __restrict__ out)
{
    __shared__ ScanSM sm;
    const int tid = threadIdx.x;
    int* aggF = cnt + 108 * 32;                  // aggregated scan epoch
    int* pF   = cnt + 110 * 32;                  // 156 prologue flags

    if (blockIdx.x >= B_) {
        const int hb = blockIdx.x - B_;          // 0..223

        // ============ phase 0: prologue tiles (helpers 0..155) ============
        if (hb < 156) {
            const int team = tid >> 8, t0 = tid & 255;
            if (hb < 60) {
                int e = hb * 2 + team;           // 0..119 energy tiles
                gemm_team<1, false>(t0, enc_h, attn_W, attn_b, energy,
                                    512, 1024, 1024, nullptr,
                                    (e & 3) * 128, (e >> 2) * 64,
                                    sm.p.As[team], sm.p.Bs[team]);
            } else {
                int p = (hb - 60) * 2 + team;    // 0..191 pre tiles
                gemm_team<0, true>(t0, embed_W, inp_W, inp_b, pre,
                                   1024, 512, 512, target,
                                   (p & 7) * 128, (p >> 3) * 64,
                                   sm.p.As[team], sm.p.Bs[team]);
            }
            asm volatile("s_waitcnt vmcnt(0)" ::: "memory");
            __syncthreads();
            if (tid == 0) st_coh_u32(&pF[hb], 1);
            __syncthreads();                     // LDS handoff to transpose
        }

        // ============ phase 1: out_W -> Wt bf16 (sc0sc1 stores) ============
        {
            const int g = tid >> 8;              // 2 tile-groups per block
            const int tt0 = tid & 255;
            const int r = tt0 >> 3, c4 = (tt0 & 7) * 4;
            float* til = sm.til;                 // [2][32][33]
            #pragma unroll 1
            for (int j = 0; j < 57; ++j) {
                const int tt = hb * 2 + g + j * 448;
                const bool act = tt < (NPAD / 32) * 16;
                int n0 = 0, k0 = 0;
                if (act) {
                    n0 = (tt >> 4) * 32;
                    k0 = (tt & 15) * 32;
                    #pragma unroll
                    for (int jj = 0; jj < 4; ++jj) {
                        int n = n0 + c4 + jj;
                        til[(g * 32 + r) * 33 + c4 + jj] =
                            (n < V_) ? __builtin_nontemporal_load(&outW[(size_t)(k0 + r) * V_ + n]) : 0.f;
                    }
                }
                __syncthreads();
                if (act) {
                    const int n = n0 + r;
                    unsigned lo = (unsigned)f2bf(til[(g * 32 + c4 + 0) * 33 + r])
                                | ((unsigned)f2bf(til[(g * 32 + c4 + 1) * 33 + r]) << 16);
                    unsigned hi2 = (unsigned)f2bf(til[(g * 32 + c4 + 2) * 33 + r])
                                 | ((unsigned)f2bf(til[(g * 32 + c4 + 3) * 33 + r]) << 16);
                    unsigned long long ov = (unsigned long long)lo | ((unsigned long long)hi2 << 32);
                    st_coh_u64((unsigned long long*)&Wt[(size_t)n * 512 + k0 + c4], ov);
                }
                __syncthreads();
            }
        }

        // ============ helper barrier: all Wt tiles LLC-visible ============
        {
            int* hF = cnt + 101 * 32;            // 224 flags
            asm volatile("s_waitcnt vmcnt(0)" ::: "memory");
            __syncthreads();
            if (tid == 0) st_coh_u32(&hF[hb], 1);
            if (tid < 64) {
                for (;;) {
                    int ok = 1;
                    #pragma unroll
                    for (int q = 0; q < 4; ++q) {
                        int idx = (tid & 63) + q * 64;
                        int v = (idx < 224) ? ld_coh_u32(&hF[idx]) : 1;
                        ok &= (v != 0);
                    }
                    if (__all(ok)) break;
                    __builtin_amdgcn_s_sleep(16);
                }
            }
            __syncthreads();
        }

        // ============ phase 2: column-major overlapped output GEMM ============
        const int ci = hb;
        if (ci < NCOL) {
            short* As_wt  = (short*)sm.g;               // 2 bufs x 8192 shorts
            short* Bs_dec = (short*)(sm.g + 32768);     // 2 bufs x 4096 shorts
            float* epi    = (float*)sm.g;               // epilogue staging
            const int lane = tid & 63, w = tid >> 6;
            const int wm = w >> 2, wn = w & 3;
            const int cb = ci * 256;

#define STAGE_TILE(bix, kt, rb) do {                                          \
            short* Ab_ = As_wt + (bix) * 8192;                                \
            short* Bb_ = Bs_dec + (bix) * 4096;                               \
            _Pragma("unroll")                                                 \
            for (int j_ = 0; j_ < 2; ++j_) {                                  \
                int rg_ = w * 2 + j_;                                         \
                int row_ = rg_ * 16 + (lane >> 2);                            \
                int kc_ = (lane & 3) ^ (row_ & 3);                            \
                gload_lds16(Wt + ((size_t)(cb + row_) * 512 + (kt) * 32 + kc_ * 8), \
                            Ab_ + rg_ * 512);                                 \
            }                                                                 \
            {                                                                 \
                int row_ = w * 16 + (lane >> 2);                              \
                int kc_ = (lane & 3) ^ (row_ & 3);                            \
                gload_lds16(dec_b + (((size_t)((kt) * 2 + (kc_ >> 1)) * 1536 + ((rb) + row_)) * 16 \
                                     + (kc_ & 1) * 8),                        \
                            Bb_ + w * 512);                                   \
            }                                                                 \
        } while (0)

            #pragma unroll 1
            for (int rbi = 0; rbi < 12; ++rbi) {
                const int rb   = rbi * 128;
                const int need = rbi * 4 + 4;    // dec rows final at aggF >= need

                if (tid < 64) {
                    for (;;) {
                        int v = ld_coh_u32(aggF);
                        if (__all(v >= need)) break;
                        __builtin_amdgcn_s_sleep(32);
                    }
                }
                __syncthreads();

                f32x4v acc[4][4];
                #pragma unroll
                for (int mi = 0; mi < 4; ++mi)
                    #pragma unroll
                    for (int ni = 0; ni < 4; ++ni) acc[mi][ni] = (f32x4v)0.f;

                STAGE_TILE(0, 0, rb);

                #pragma unroll 1
                for (int it = 0; it < 16; ++it) {
                    const int cur = it & 1;
                    __builtin_amdgcn_s_barrier();        // A: compute of it-1 done
                    asm volatile("" ::: "memory");
                    if (it < 15) {
                        STAGE_TILE(cur ^ 1, it + 1, rb);
                        asm volatile("s_waitcnt vmcnt(3)" ::: "memory");
                    } else {
                        asm volatile("s_waitcnt vmcnt(0)" ::: "memory");
                    }
                    __builtin_amdgcn_s_barrier();        // B: it-tile loads landed
                    asm volatile("" ::: "memory");

                    const short* Ab = As_wt + cur * 8192;
                    const short* Bb = Bs_dec + cur * 4096;
                    bf16x8v af[4], bf[4];
                    const int lc = lane >> 4;            // k-chunk 0..3
                    #pragma unroll
                    for (int ni = 0; ni < 4; ++ni) {
                        int r_ = wn * 64 + ni * 16 + (lane & 15);
                        af[ni] = *(const bf16x8v*)&Ab[r_ * 32 + ((lc ^ (r_ & 3)) * 8)];
                    }
                    #pragma unroll
                    for (int mi = 0; mi < 4; ++mi) {
                        int r_ = wm * 64 + mi * 16 + (lane & 15);
                        bf[mi] = *(const bf16x8v*)&Bb[r_ * 32 + ((lc ^ (r_ & 3)) * 8)];
                    }
                    #pragma unroll
                    for (int mi = 0; mi < 4; ++mi)
                        #pragma unroll
                        for (int ni = 0; ni < 4; ++ni)
                            acc[mi][ni] = __builtin_amdgcn_mfma_f32_16x16x32_bf16(
                                af[ni], bf[mi], acc[mi][ni], 0, 0, 0);
                }

                // ---- coalesced epilogue via LDS ----
                const int c4e = (tid & 63) * 4;
                const bool fullcols = (cb + 256 <= V_);
                f32x4v bq = (f32x4v)0.f;
                if (fullcols) {
                    float4 t4 = *(const float4*)(out_b + cb + c4e);
                    bq[0] = t4.x; bq[1] = t4.y; bq[2] = t4.z; bq[3] = t4.w;
                }
                #pragma unroll
                for (int mi = 0; mi < 4; ++mi) {
                    __syncthreads();              // epi region free
                    #pragma unroll
                    for (int ni = 0; ni < 4; ++ni) {
                        const int er = wm * 16 + (lane & 15);
                        const int ec = wn * 64 + ni * 16 + (lane >> 4) * 4;
                        *(f32x4v*)&epi[er * EPI_LD + ec] = acc[mi][ni];
                    }
                    __syncthreads();
                    #pragma unroll
                    for (int j = 0; j < 4; ++j) {
                        const int rr = w + j * 8; // 0..31
                        const int orow = rb + (rr >> 4) * 64 + mi * 16 + (rr & 15);
                        f32x4v v = *(const f32x4v*)&epi[rr * EPI_LD + c4e];
                        if (fullcols) {
                            v += bq;
                            *(f32x4a*)(out + (size_t)orow * V_ + cb + c4e) = v;
                        } else {
                            #pragma unroll
                            for (int vv = 0; vv < 4; ++vv) {
                                const int col = cb + c4e + vv;
                                if (col < V_)
                                    out[(size_t)orow * V_ + col] = v[vv] + out_b[col];
                            }
                        }
                    }
                }
            }
#undef STAGE_TILE
        }
        return;
    }

    // ---------------- cooperative scan ----------------
    const int bi = blockIdx.x;                   // batch (phase A) / col-slice (phase B)
    const int lane = tid & 63, wv = tid >> 6;    // 8 waves
    float (*eL)[H_] = sm.s.eL;
    float* part   = sm.s.part;
    float* sA     = part;                        // overlays (phase A only)
    float* scoreL = part + 512;
    float* alphaL = part + 576;
    float* sCol   = sm.s.sCol;
    int*   sF     = cnt + 100 * 32;              // s-epoch flags (32 ints)

    // ---- weight fragments first (independent of prologue) ----
    bf16x8v wf0[2][2], wf1[2][2];
    {
        const int l15 = lane & 15, lc = lane >> 4;
        #pragma unroll
        for (int ktl = 0; ktl < 2; ++ktl)
            #pragma unroll
            for (int nt = 0; nt < 2; ++nt) {
                const int kb = (wv * 2 + ktl) * 32 + lc * 8;
                const int n  = nt * 512 + bi * 16 + l15;
                #pragma unroll
                for (int jj = 0; jj < 8; ++jj) {
                    wf0[ktl][nt][jj] = (short)f2bf(cell_W[((size_t)(kb + jj)) * 1024 + n]);
                    wf1[ktl][nt][jj] = (short)f2bf(cell_W[((size_t)(512 + kb + jj)) * 1024 + n]);
                }
            }
    }
    const int hME = bi * 16 + (tid & 15);
    sCol[tid] = prev_s[(size_t)(tid >> 4) * 512 + hME];
    const float cb0h = cell_b[hME],        cb0t = cell_b[512 + hME];
    const float cb1h = cell_b[1024 + hME], cb1t = cell_b[1536 + hME];

    // ---- prologue gate: all 156 energy/pre tiles done & LLC-visible ----
    if (tid < 64) {
        for (;;) {
            int ok = 1;
            #pragma unroll
            for (int q = 0; q < 3; ++q) {
                int idx = tid + q * 64;
                int v = (idx < 156) ? ld_coh_u32(&pF[idx]) : 1;
                ok &= (v != 0);
            }
            if (__all(ok)) break;
            __builtin_amdgcn_s_sleep(8);
        }
    }
    __syncthreads();

    // ---- load energy slice into LDS (plain gated reads; float4) ----
    for (int i = tid; i < S_ * H_ / 4; i += 512) {
        int s = i >> 7, h4 = (i & 127) * 4;
        *(float4*)&eL[s][h4] = *(const float4*)&energy[((size_t)bi * S_ + s) * 512 + h4];
    }

    #pragma unroll 1
    for (int t = 0; t < T_; ++t) {
        // ================= phase A (batch role, b = bi) =================
        float sAv;
        if (t == 0) {
            sAv = prev_s[(size_t)bi * 512 + tid];
            __syncthreads();                     // part region free
            sA[tid] = sAv;
            __syncthreads();
        } else {
            const int* fp = &sF[tid >> 4];
            for (;;) {
                int v = ld_coh_u32(fp);
                if (v >= t) break;
                __builtin_amdgcn_s_sleep(1);
            }
            sAv = ld_coh_f32_nw(sG + ((size_t)(tid >> 4) * 32 + bi) * 16 + (tid & 15));
            __syncthreads();                     // overlaps the sG round-trip
            asm volatile("s_waitcnt vmcnt(0)" ::: "memory");
            sA[tid] = sAv;
            __syncthreads();
            // block 0 proved all sF >= t -> publish aggregated epoch
            if (bi == 0 && tid == 0)
                st_coh_u32(aggF, t);
        }

        // ---- scores (energy from LDS; 2-row ILP per wave) ----
        #pragma unroll 1
        for (int sp = 0; sp < 4; ++sp) {
            const int s0 = wv + sp * 16;
            const int s1 = s0 + 8;
            const bool has1 = (sp < 3) | (wv < 4);
            const float* e0 = &eL[s0][lane];
            const float* e1 = &eL[has1 ? s1 : s0][lane];
            float a0 = 0.f, a1 = 0.f;
            #pragma unroll
            for (int j = 0; j < 8; ++j) {
                float sv = sA[lane + j * 64];
                a0 = fmaf(e0[j * 64], sv, a0);
                a1 = fmaf(e1[j * 64], sv, a1);
            }
            #pragma unroll
            for (int off = 32; off; off >>= 1) {
                a0 += __shfl_xor(a0, off, 64);
                a1 += __shfl_xor(a1, off, 64);
            }
            if (lane == 0) {
                scoreL[s0] = a0;
                if (has1) scoreL[s1] = a1;
            }
        }
        __syncthreads();
        // ---- softmax (wave 0) ----
        if (wv == 0) {
            float v = (lane < S_) ? scoreL[lane] : -3.4e38f;
            float m = v;
            #pragma unroll
            for (int off = 32; off; off >>= 1) m = fmaxf(m, __shfl_xor(m, off, 64));
            float e = (lane < S_) ? __expf(v - m) : 0.f;
            float su = e;
            #pragma unroll
            for (int off = 32; off; off >>= 1) su += __shfl_xor(su, off, 64);
            if (lane < S_) alphaL[lane] = e / su;
        }
        __syncthreads();
        // ---- ctx (fp32 enc_h from L2, consume-as-you-go) + x0 out ----
        {
            float a = 0.f;
            const float* ep = enc_h + (size_t)bi * S_ * 1024 + tid;
            #pragma unroll 20
            for (int s = 0; s < S_; ++s) a = fmaf(alphaL[s], ep[(size_t)s * 1024], a);
            st_coh_f32(ctxG + (size_t)bi * 512 + tid, a);
            float x0 = a * sA[tid];
            unsigned short xh = f2bf(x0);
            unsigned short xl = f2bf(x0 - bflo((unsigned)xh));
            int kt = tid >> 5, lc2 = (tid >> 3) & 3, jj = tid & 7;
            int ch = (kt * 8 + lc2) * 32 + bi;
            st_coh_u16(xG0 + (size_t)ch * 8 + jj, xh);
            st_coh_u16(xG0 + (size_t)(ch + 128) * 8 + jj, xl);
        }
        gbar(cnt, 2 * t + 0, bi);
        // ================= phase B: two highway layers =================
        highway<0>(t, bi, tid, lane, wv, wf0, xG0, xG1, ctxG, sG, dec_b, pre,
                   cb0h, cb0t, part, sCol);
        gbar(cnt, 2 * t + 1, bi);
        highway<1>(t, bi, tid, lane, wv, wf1, xG1, xG1, ctxG, sG, dec_b, pre,
                   cb1h, cb1t, part, sCol);
        // s-ready + dec(t)-ready epoch flag (drained before store)
        asm volatile("s_waitcnt vmcnt(0)" ::: "memory");
        __syncthreads();
        if (tid == 0)
            st_coh_u32(&sF[bi], t + 1);
    }

    // final aggregated publish: block 0 waits for all sF >= T_ then sets
    // aggF = T_ so rbi=11 tiles (need = 48) can proceed.
    if (bi == 0) {
        if (tid < 64) {
            const int* fp2 = &sF[tid & 31];
            for (;;) {
                int v = ld_coh_u32(fp2);
                if (__all(v >= T_)) break;
                __builtin_amdgcn_s_sleep(1);
            }
        }
        __syncthreads();
        if (tid == 0)
            st_coh_u32(aggF, T_);
    }
}

// ---------------------------------------------------------------------------
extern "C" void kernel_launch(void* const* d_in, const int* in_sizes, int n_in,
                              void* d_out, int out_size, void* d_ws, size_t ws_size,
                              hipStream_t stream)
{
    const float* enc_h   = (const float*)d_in[0];
    const float* prev_s  = (const float*)d_in[1];
    const int*   target  = (const int*)  d_in[2];
    const float* embed_W = (const float*)d_in[3];
    const float* attn_W  = (const float*)d_in[4];
    const float* attn_b  = (const float*)d_in[5];
    const float* inp_W   = (const float*)d_in[6];
    const float* inp_b   = (const float*)d_in[7];
    const float* cell_W  = (const float*)d_in[8];
    const float* cell_b  = (const float*)d_in[9];
    const float* out_W   = (const float*)d_in[10];
    const float* out_b   = (const float*)d_in[11];
    float* out = (float*)d_out;

    float* ws = (float*)d_ws;
    float* energy = ws;                                       // 983040 f
    float* pre    = energy + (size_t)B_ * S_ * H_;            // 1572864 f
    float* ctxG   = pre + (size_t)T_ * B_ * 2 * H_;           // 16384 f
    float* sG     = ctxG + (size_t)B_ * H_;                   // 16384 f
    int*   cnt    = (int*)(sG + (size_t)B_ * H_);             // 4608 i (flags)
    unsigned short* dec_b = (unsigned short*)(cnt + 144 * 32);// 786432 u16 (block-major)
    unsigned short* xG0   = dec_b + (size_t)T_ * B_ * H_;     // 32768 u16 (frag-order)
    unsigned short* xG1   = xG0 + (size_t)2 * B_ * H_;        // 32768 u16 (frag-order)
    unsigned short* Wt    = xG1 + (size_t)2 * B_ * H_;        // NPAD*512 u16

    // 0. zero all flags (stream-ordered; release at op end -> visible)
    hipMemsetAsync(cnt, 0, 144 * 32 * sizeof(int), stream);

    // 1. single fused kernel: prologue GEMMs (helper teams) || scan ||
    //    transpose || column-major output GEMM
    scan_tr<<<256, 512, 0, stream>>>(enc_h, attn_W, attn_b, energy,
                                     embed_W, inp_W, inp_b, pre, target,
                                     prev_s, cell_W, cell_b,
                                     dec_b, out_W, Wt, ctxG, sG, xG0, xG1, cnt,
                                     out_b, out);
}

// Round 11
// 793.456 us; speedup vs baseline: 1.0476x; 1.0476x over previous
//
#include <hip/hip_runtime.h>
#include <hip/hip_bf16.h>
#include <math.h>

#define B_ 32
#define S_ 60
#define T_ 48
#define H_ 512
#define E_ 512
#define V_ 50257
#define NPAD 50432   // V_ padded up to multiple of 256
#define EPI_LD 260   // padded LDS stride for epilogue staging
#define NTILE ((NPAD / 256) * 12)   // 2364 output tiles

typedef __attribute__((ext_vector_type(8))) short bf16x8v;
typedef __attribute__((ext_vector_type(4))) float f32x4v;
typedef __attribute__((ext_vector_type(4))) float f32x4a __attribute__((aligned(4)));
typedef __attribute__((ext_vector_type(4))) unsigned int u32x4;

__device__ inline unsigned short f2bf(float f) {
    union { float f; unsigned u; } v; v.f = f;
    unsigned r = v.u + 0x7fffu + ((v.u >> 16) & 1u);   // round-to-nearest-even
    return (unsigned short)(r >> 16);
}
__device__ inline float bflo(unsigned u) { return __uint_as_float(u << 16); }

__device__ inline void gload_lds16(const void* g, void* l) {
    __builtin_amdgcn_global_load_lds(
        (const __attribute__((address_space(1))) unsigned int*)g,
        (__attribute__((address_space(3))) unsigned int*)l, 16, 0, 0);
}

// ---------------------------------------------------------------------------
// LLC-coherent (cache-bypassing) access helpers. sc0+sc1 => read/write at the
// coherence point. Rules (r4/r7 post-mortems):
//  - cells READ by other blocks in-flight (flags, sG, ctxG, xG*) are touched
//    ONLY via sc0sc1 on both sides;
//  - write-once buffers (Wt, dec_b) are WRITTEN sc0sc1 (write-through, no
//    dirty/cached L2 copies) and may be READ PLAIN after a ready-gate.
// ---------------------------------------------------------------------------
__device__ __forceinline__ float ld_coh_f32_nw(const float* p) {   // no wait
    float r;
    asm volatile("global_load_dword %0, %1, off sc0 sc1"
                 : "=v"(r) : "v"(p) : "memory");
    return r;
}
__device__ __forceinline__ void st_coh_f32(float* p, float v) {
    asm volatile("global_store_dword %0, %1, off sc0 sc1"
                 :: "v"(p), "v"(v) : "memory");
}
__device__ __forceinline__ void st_coh_u16(unsigned short* p, unsigned int v) {
    asm volatile("global_store_short %0, %1, off sc0 sc1"
                 :: "v"(p), "v"(v) : "memory");
}
__device__ __forceinline__ void st_coh_u32(int* p, int v) {
    asm volatile("global_store_dword %0, %1, off sc0 sc1"
                 :: "v"(p), "v"(v) : "memory");
}
__device__ __forceinline__ void st_coh_u64(unsigned long long* p, unsigned long long v) {
    asm volatile("global_store_dwordx2 %0, %1, off sc0 sc1"
                 :: "v"(p), "v"(v) : "memory");
}
__device__ __forceinline__ int ld_coh_u32(const int* p) {
    int r;
    asm volatile("global_load_dword %0, %1, off sc0 sc1\n\ts_waitcnt vmcnt(0)"
                 : "=v"(r) : "v"(p) : "memory");
    return r;
}
__device__ __forceinline__ u32x4 ld_cohx4(const void* p) {
    u32x4 r;
    asm volatile("global_load_dwordx4 %0, %1, off sc0 sc1"
                 : "=v"(r) : "v"(p) : "memory");
    return r;                     // caller must s_waitcnt vmcnt(0) before use
}

// ---------------------------------------------------------------------------
// 32-block device barrier, flag-array form.
// ---------------------------------------------------------------------------
__device__ __forceinline__ void gbar(int* flags, int idx, int bi) {
    asm volatile("s_waitcnt vmcnt(0)" ::: "memory");
    __syncthreads();
    if (threadIdx.x == 0)
        st_coh_u32(&flags[idx * 32 + bi], 1);
    if (threadIdx.x < 64) {
        const int* fp = &flags[idx * 32 + (threadIdx.x & 31)];
        for (;;) {
            int v = ld_coh_u32(fp);
            if (__all(v != 0)) break;
            __builtin_amdgcn_s_sleep(1);
        }
    }
    __syncthreads();
}

// ---------------------------------------------------------------------------
// fp32 tiled GEMM body; 256 threads, MR x 128 tile (MR=128 or 64), BK=8.
// MR=64 halves per-block work to balance the prologue across more CUs.
// ---------------------------------------------------------------------------
template<int ACT, bool GATHER, int MR>
__device__ void gemm_body(const float* __restrict__ A, const float* __restrict__ Bm,
                          const float* __restrict__ bias, float* __restrict__ C,
                          int N, int K, int lda, const int* __restrict__ gidx,
                          int cb, int rb, float (*As)[128], float (*Bs)[128])
{
    const int tid = threadIdx.x;
    const int am = (MR == 128) ? (tid >> 1) : ((tid & 127) >> 1);
    const int ak = (tid & 1) * 4;
    const bool aact = (MR == 128) || (tid < 128);
    const int arow = rb + am;
    const float* Arow;
    if (GATHER) Arow = A + (size_t)gidx[arow] * lda;
    else        Arow = A + (size_t)arow * lda;

    const int bk = tid >> 5;
    const int bn = (tid & 31) * 4;

    const int tx = tid & 15, ty = tid >> 4;
    float acc[MR / 16][8];
    #pragma unroll
    for (int i = 0; i < MR / 16; i++)
        #pragma unroll
        for (int j = 0; j < 8; j++) acc[i][j] = 0.f;

    for (int k0 = 0; k0 < K; k0 += 8) {
        float4 av, bv;
        if (aact) av = *(const float4*)(Arow + k0 + ak);
        bv = *(const float4*)(Bm + (size_t)(k0 + bk) * N + cb + bn);
        __syncthreads();
        if (aact) {
            As[ak + 0][am] = av.x; As[ak + 1][am] = av.y;
            As[ak + 2][am] = av.z; As[ak + 3][am] = av.w;
        }
        Bs[bk][bn + 0] = bv.x; Bs[bk][bn + 1] = bv.y;
        Bs[bk][bn + 2] = bv.z; Bs[bk][bn + 3] = bv.w;
        __syncthreads();

        #pragma unroll
        for (int k = 0; k < 8; k++) {
            float a[MR / 16], b[8];
            if constexpr (MR == 128) {
                *(float4*)(a)     = *(const float4*)&As[k][ty * 4];
                *(float4*)(a + 4) = *(const float4*)&As[k][ty * 4 + 64];
            } else {
                *(float4*)(a)     = *(const float4*)&As[k][ty * 4];
            }
            *(float4*)(b)     = *(const float4*)&Bs[k][tx * 4];
            *(float4*)(b + 4) = *(const float4*)&Bs[k][tx * 4 + 64];
            #pragma unroll
            for (int i = 0; i < MR / 16; i++)
                #pragma unroll
                for (int j = 0; j < 8; j++)
                    acc[i][j] = fmaf(a[i], b[j], acc[i][j]);
        }
    }

    #pragma unroll
    for (int i = 0; i < MR / 16; i++) {
        int row;
        if constexpr (MR == 128)
            row = rb + ((i < 4) ? (ty * 4 + i) : (64 + ty * 4 + (i - 4)));
        else
            row = rb + ty * 4 + i;
        #pragma unroll
        for (int j = 0; j < 8; j++) {
            int col = cb + ((j < 4) ? (tx * 4 + j) : (64 + tx * 4 + (j - 4)));
            float v = acc[i][j] + bias[col];
            if (ACT == 1) v = tanhf(v);
            C[(size_t)row * N + col] = v;
        }
    }
}

// ---------------------------------------------------------------------------
// Merged prologue (balanced): blocks 0..119 = energy gemm (64x128 tiles,
// tanh), 120..215 = pre gemm (128x128, gathered), 216 = zero flags (sc0sc1).
//   rows 0..95   : gbar flags; row 100: sF; rows 101..107: hF; row 108: aggF
// ---------------------------------------------------------------------------
__global__ __launch_bounds__(256)
void gemm_pro(const float* __restrict__ enc_h, const float* __restrict__ attn_W,
              const float* __restrict__ attn_b, float* __restrict__ energy,
              const float* __restrict__ embed_W, const float* __restrict__ inp_W,
              const float* __restrict__ inp_b, float* __restrict__ pre,
              const int* __restrict__ target, int* __restrict__ cnt)
{
    __shared__ float As[8][128];
    __shared__ float Bs[8][128];
    const int bx = blockIdx.x;
    if (bx < 120) {
        // energy: M=1920 N=512 K=1024; 64x128 tiles, grid (4,30)
        const int cb = (bx & 3) * 128, rb = (bx >> 2) * 64;
        gemm_body<1, false, 64>(enc_h, attn_W, attn_b, energy,
                                512, 1024, 1024, nullptr, cb, rb, As, Bs);
    } else if (bx < 216) {
        // pre: M=1536 N=1024 K=512; 128x128 tiles, grid (8,12)
        const int b2 = bx - 120;
        const int cb = (b2 & 7) * 128, rb = (b2 >> 3) * 128;
        gemm_body<0, true, 128>(embed_W, inp_W, inp_b, pre,
                                1024, 512, 512, target, cb, rb, As, Bs);
    } else {
        for (int i = threadIdx.x; i < 144 * 32; i += 256)
            st_coh_u32(&cnt[i], 0);
    }
}

// ---------------------------------------------------------------------------
// Scan LDS (scan path) / transpose tiles + gemm smem (helper path).
// ---------------------------------------------------------------------------
union __align__(16) ScanSM {
    struct {
        float eL[S_][H_];        // 122880 B
        float part[8 * 32 * 36]; // 36864 B; overlay: sA[0..511] score[512..575] alpha[576..639]
        float sCol[512];         // 2048 B
    } s;
    float til[2 * 32 * 33];      // transpose tiles (helper, phase 1)
    char g[49152];               // gemm smem (helper, phase 2)
};

// ---------------------------------------------------------------------------
// x exchange buffers in MFMA-FRAGMENT order (direct LLC fragment loads).
// ---------------------------------------------------------------------------
template<int LI>
__device__ __forceinline__ void highway(
    int t, int bi, int tid, int lane, int wv,
    const bf16x8v (&wf)[2][2],
    const unsigned short* __restrict__ xsrc,
    unsigned short* __restrict__ xG1,
    const float* __restrict__ ctxG,
    float* __restrict__ sG,
    unsigned short* __restrict__ dec_b,
    const float* __restrict__ pre,
    float cbh, float cbt,
    float* part, float* sCol)
{
    const int l15 = lane & 15, lc = lane >> 4;
    const int b = tid >> 4, hi = tid & 15;
    const int h = bi * 16 + hi;

    // ---- issue cross-block ctx load + pre loads early (latency hidden) ----
    float cxv = 0.f, prh = 0.f, prt = 0.f;
    if (LI == 0) {
        cxv = ld_coh_f32_nw(ctxG + (size_t)b * 512 + h);
        const float* pr = pre + ((size_t)t * B_ + b) * 1024;
        prh = pr[h]; prt = pr[h + 512];
    }

    // ---- direct per-lane fragment loads from LLC (8 x 16B per lane) ----
    u32x4 xr[2][2][2];                       // [ktl][pl][mt]
    #pragma unroll
    for (int ktl = 0; ktl < 2; ++ktl)
        #pragma unroll
        for (int pl = 0; pl < 2; ++pl)
            #pragma unroll
            for (int mt = 0; mt < 2; ++mt) {
                int ch = (((wv * 2 + ktl) * 2 + pl) * 4 + lc) * 32 + mt * 16 + l15;
                xr[ktl][pl][mt] = ld_cohx4(xsrc + (size_t)ch * 8);
            }
    asm volatile("s_waitcnt vmcnt(0)" ::: "memory");
    __builtin_amdgcn_sched_barrier(0);

    // ---- MFMA: wave wv owns k-tiles {2wv, 2wv+1} ----
    f32x4v acc[2][2];
    #pragma unroll
    for (int mt = 0; mt < 2; ++mt)
        #pragma unroll
        for (int nt = 0; nt < 2; ++nt) acc[mt][nt] = (f32x4v)0.f;

    #pragma unroll
    for (int ktl = 0; ktl < 2; ++ktl)
        #pragma unroll
        for (int pl = 0; pl < 2; ++pl)
            #pragma unroll
            for (int mt = 0; mt < 2; ++mt) {
                bf16x8v xv = *(bf16x8v*)&xr[ktl][pl][mt];
                #pragma unroll
                for (int nt = 0; nt < 2; ++nt)
                    acc[mt][nt] = __builtin_amdgcn_mfma_f32_16x16x32_bf16(
                        wf[ktl][nt], xv, acc[mt][nt], 0, 0, 0);
            }

    #pragma unroll
    for (int mt = 0; mt < 2; ++mt)
        #pragma unroll
        for (int nt = 0; nt < 2; ++nt)
            *(f32x4v*)&part[(wv * 32 + mt * 16 + l15) * 36 + nt * 16 + lc * 4] = acc[mt][nt];
    __syncthreads();

    // ---- 8-way reduce + gates; thread tid -> (b = tid>>4, hi = tid&15) ----
    float rh = 0.f, rt = 0.f;
    #pragma unroll
    for (int w = 0; w < 8; ++w) {
        rh += part[(w * 32 + b) * 36 + hi];
        rt += part[(w * 32 + b) * 36 + 16 + hi];
    }
    float ph = rh + cbh, pt = rt + cbt;
    if (LI == 0) { ph += prh; pt += prt; }
    float hh = tanhf(ph);
    float tg = 1.f / (1.f + __expf(-pt));
    float sold = sCol[tid];
    float sn = hh * tg + sold * (1.f - tg);
    sCol[tid] = sn;
    if (LI == 0) {
        float x1 = sn * cxv;
        unsigned short xh = f2bf(x1);
        unsigned short xl = f2bf(x1 - bflo((unsigned)xh));
        int kt = h >> 5, lc2 = (h >> 3) & 3, jj = h & 7;
        int ch = (kt * 8 + lc2) * 32 + b;
        st_coh_u16(xG1 + (size_t)ch * 8 + jj, xh);
        st_coh_u16(xG1 + (size_t)(ch + 128) * 8 + jj, xl);
    } else {
        st_coh_f32(sG + ((size_t)bi * 32 + b) * 16 + hi, sn);
        st_coh_u16(dec_b + ((size_t)bi * 1536 + (size_t)t * B_ + b) * 16 + hi,
                   f2bf(sn));
    }
}

// ---------------------------------------------------------------------------
// Combined kernel:
//   blocks 0..31   = cooperative scan; block 0 additionally publishes the
//                    aggregated epoch aggF = t (proved by its phase-A poll).
//   blocks 32..255 = out_W transpose -> helper barrier -> overlapped output
//                    GEMM, tiles gated on aggF; gate-exit STAGGERED per
//                    helper to de-burst LLC traffic (r10 post-mortem).
// Helpers never block the scan; scan never waits on helpers -> no cycles.
// ---------------------------------------------------------------------------
__global__ __launch_bounds__(512, 2)
void scan_tr(const float* __restrict__ energy, const float* __restrict__ enc_h,
             const float* __restrict__ prev_s, const float* __restrict__ pre,
             const float* __restrict__ cell_W, const float* __restrict__ cell_b,
             unsigned short* __restrict__ dec_b,
             const float* __restrict__ outW, unsigned short* __restrict__ Wt,
             float* __restrict__ ctxG, float* __restrict__ sG,
             unsigned short* __restrict__ xG0, unsigned short* __restrict__ xG1,
             int* __restrict__ cnt,
             const float* __restrict__ out_b, float* __restrict__ out)
{
    __shared__ ScanSM sm;
    const int tid = threadIdx.x;
    int* aggF = cnt + 108 * 32;                  // aggregated scan epoch

    if (blockIdx.x >= B_) {
        // ============ helper phase 1: out_W -> Wt bf16 (sc0sc1 stores) ============
        const int hb = blockIdx.x - B_;          // 0..223
        const int g = tid >> 8;                  // 2 tile-groups per block
        const int tt0 = tid & 255;
        const int r = tt0 >> 3, c4 = (tt0 & 7) * 4;
        float* til = sm.til;                     // [2][32][33]
        #pragma unroll 1
        for (int j = 0; j < 57; ++j) {
            const int tt = hb * 2 + g + j * 448;
            const bool act = tt < (NPAD / 32) * 16;
            int n0 = 0, k0 = 0;
            if (act) {
                n0 = (tt >> 4) * 32;
                k0 = (tt & 15) * 32;
                #pragma unroll
                for (int jj = 0; jj < 4; ++jj) {
                    int n = n0 + c4 + jj;
                    til[(g * 32 + r) * 33 + c4 + jj] =
                        (n < V_) ? __builtin_nontemporal_load(&outW[(size_t)(k0 + r) * V_ + n]) : 0.f;
                }
            }
            __syncthreads();
            if (act) {
                const int n = n0 + r;
                unsigned lo = (unsigned)f2bf(til[(g * 32 + c4 + 0) * 33 + r])
                            | ((unsigned)f2bf(til[(g * 32 + c4 + 1) * 33 + r]) << 16);
                unsigned hi2 = (unsigned)f2bf(til[(g * 32 + c4 + 2) * 33 + r])
                             | ((unsigned)f2bf(til[(g * 32 + c4 + 3) * 33 + r]) << 16);
                unsigned long long ov = (unsigned long long)lo | ((unsigned long long)hi2 << 32);
                st_coh_u64((unsigned long long*)&Wt[(size_t)n * 512 + k0 + c4], ov);
            }
            __syncthreads();
        }

        // ============ helper barrier: all Wt tiles LLC-visible ============
        {
            int* hF = cnt + 101 * 32;            // 224 flags
            asm volatile("s_waitcnt vmcnt(0)" ::: "memory");
            __syncthreads();
            if (tid == 0) st_coh_u32(&hF[hb], 1);
            if (tid < 64) {
                for (;;) {
                    int ok = 1;
                    #pragma unroll
                    for (int q = 0; q < 4; ++q) {
                        int idx = (tid & 63) + q * 64;
                        int v = (idx < 224) ? ld_coh_u32(&hF[idx]) : 1;
                        ok &= (v != 0);
                    }
                    if (__all(ok)) break;
                    __builtin_amdgcn_s_sleep(16);
                }
            }
            __syncthreads();
        }

        // ============ helper phase 2: overlapped output GEMM ============
        {
            short* As_wt  = (short*)sm.g;               // 2 bufs x 8192 shorts
            short* Bs_dec = (short*)(sm.g + 32768);     // 2 bufs x 4096 shorts
            float* epi    = (float*)sm.g;               // epilogue staging
            const int lane = tid & 63, w = tid >> 6;
            const int wm = w >> 2, wn = w & 3;

#define STAGE_TILE(bix, kt, rb, cb) do {                                      \
            short* Ab_ = As_wt + (bix) * 8192;                                \
            short* Bb_ = Bs_dec + (bix) * 4096;                               \
            _Pragma("unroll")                                                 \
            for (int j_ = 0; j_ < 2; ++j_) {                                  \
                int rg_ = w * 2 + j_;                                         \
                int row_ = rg_ * 16 + (lane >> 2);                            \
                int kc_ = (lane & 3) ^ (row_ & 3);                            \
                gload_lds16(Wt + ((size_t)((cb) + row_) * 512 + (kt) * 32 + kc_ * 8), \
                            Ab_ + rg_ * 512);                                 \
            }                                                                 \
            {                                                                 \
                int row_ = w * 16 + (lane >> 2);                              \
                int kc_ = (lane & 3) ^ (row_ & 3);                            \
                gload_lds16(dec_b + (((size_t)((kt) * 2 + (kc_ >> 1)) * 1536 + ((rb) + row_)) * 16 \
                                     + (kc_ & 1) * 8),                        \
                            Bb_ + w * 512);                                   \
            }                                                                 \
        } while (0)

            #pragma unroll 1
            for (int i = hb; i < NTILE; i += 224) {
                const int rbi = i / 197;             // 0..11 (monotone per helper)
                const int rb  = rbi * 128;
                const int cb  = (i % 197) * 256;
                const int need = rbi * 4 + 4;        // dec rows final at aggF >= need

                if (tid < 64) {
                    // stagger pollers/stagers to de-burst LLC traffic
                    #pragma unroll 1
                    for (int z = 0; z < (hb & 31); ++z)
                        __builtin_amdgcn_s_sleep(8);
                    for (;;) {
                        int v = ld_coh_u32(aggF);
                        if (__all(v >= need)) break;
                        __builtin_amdgcn_s_sleep(64);
                    }
                }
                __syncthreads();

                f32x4v acc[4][4];
                #pragma unroll
                for (int mi = 0; mi < 4; ++mi)
                    #pragma unroll
                    for (int ni = 0; ni < 4; ++ni) acc[mi][ni] = (f32x4v)0.f;

                STAGE_TILE(0, 0, rb, cb);

                #pragma unroll 1
                for (int it = 0; it < 16; ++it) {
                    const int cur = it & 1;
                    __builtin_amdgcn_s_barrier();        // A: compute of it-1 done
                    asm volatile("" ::: "memory");
                    if (it < 15) {
                        STAGE_TILE(cur ^ 1, it + 1, rb, cb);
                        asm volatile("s_waitcnt vmcnt(3)" ::: "memory");
                    } else {
                        asm volatile("s_waitcnt vmcnt(0)" ::: "memory");
                    }
                    __builtin_amdgcn_s_barrier();        // B: it-tile loads landed
                    asm volatile("" ::: "memory");

                    const short* Ab = As_wt + cur * 8192;
                    const short* Bb = Bs_dec + cur * 4096;
                    bf16x8v af[4], bf[4];
                    const int lc = lane >> 4;            // k-chunk 0..3
                    #pragma unroll
                    for (int ni = 0; ni < 4; ++ni) {
                        int r_ = wn * 64 + ni * 16 + (lane & 15);
                        af[ni] = *(const bf16x8v*)&Ab[r_ * 32 + ((lc ^ (r_ & 3)) * 8)];
                    }
                    #pragma unroll
                    for (int mi = 0; mi < 4; ++mi) {
                        int r_ = wm * 64 + mi * 16 + (lane & 15);
                        bf[mi] = *(const bf16x8v*)&Bb[r_ * 32 + ((lc ^ (r_ & 3)) * 8)];
                    }
                    #pragma unroll
                    for (int mi = 0; mi < 4; ++mi)
                        #pragma unroll
                        for (int ni = 0; ni < 4; ++ni)
                            acc[mi][ni] = __builtin_amdgcn_mfma_f32_16x16x32_bf16(
                                af[ni], bf[mi], acc[mi][ni], 0, 0, 0);
                }

                // ---- coalesced epilogue via LDS ----
                const int c4e = (tid & 63) * 4;
                const bool fullcols = (cb + 256 <= V_);
                f32x4v bq = (f32x4v)0.f;
                if (fullcols) {
                    float4 t4 = *(const float4*)(out_b + cb + c4e);
                    bq[0] = t4.x; bq[1] = t4.y; bq[2] = t4.z; bq[3] = t4.w;
                }
                #pragma unroll
                for (int mi = 0; mi < 4; ++mi) {
                    __syncthreads();              // epi region free
                    #pragma unroll
                    for (int ni = 0; ni < 4; ++ni) {
                        const int er = wm * 16 + (lane & 15);
                        const int ec = wn * 64 + ni * 16 + (lane >> 4) * 4;
                        *(f32x4v*)&epi[er * EPI_LD + ec] = acc[mi][ni];
                    }
                    __syncthreads();
                    #pragma unroll
                    for (int j = 0; j < 4; ++j) {
                        const int rr = w + j * 8; // 0..31
                        const int orow = rb + (rr >> 4) * 64 + mi * 16 + (rr & 15);
                        f32x4v v = *(const f32x4v*)&epi[rr * EPI_LD + c4e];
                        if (fullcols) {
                            v += bq;
                            *(f32x4a*)(out + (size_t)orow * V_ + cb + c4e) = v;
                        } else {
                            #pragma unroll
                            for (int vv = 0; vv < 4; ++vv) {
                                const int col = cb + c4e + vv;
                                if (col < V_)
                                    out[(size_t)orow * V_ + col] = v[vv] + out_b[col];
                            }
                        }
                    }
                }
            }
#undef STAGE_TILE
        }
        return;
    }

    // ---------------- cooperative scan (r6 structure) ----------------
    const int bi = blockIdx.x;                   // batch (phase A) / col-slice (phase B)
    const int lane = tid & 63, wv = tid >> 6;    // 8 waves
    float (*eL)[H_] = sm.s.eL;
    float* part   = sm.s.part;
    float* sA     = part;                        // overlays (phase A only)
    float* scoreL = part + 512;
    float* alphaL = part + 576;
    float* sCol   = sm.s.sCol;
    int*   sF     = cnt + 100 * 32;              // s-epoch flags (32 ints)

    // ---- load energy slice into LDS once (float4) ----
    for (int i = tid; i < S_ * H_ / 4; i += 512) {
        int s = i >> 7, h4 = (i & 127) * 4;
        *(float4*)&eL[s][h4] = *(const float4*)&energy[((size_t)bi * S_ + s) * 512 + h4];
    }

    // ---- weight fragments: both layers, resident for the whole scan ----
    bf16x8v wf0[2][2], wf1[2][2];
    {
        const int l15 = lane & 15, lc = lane >> 4;
        #pragma unroll
        for (int ktl = 0; ktl < 2; ++ktl)
            #pragma unroll
            for (int nt = 0; nt < 2; ++nt) {
                const int kb = (wv * 2 + ktl) * 32 + lc * 8;
                const int n  = nt * 512 + bi * 16 + l15;
                #pragma unroll
                for (int jj = 0; jj < 8; ++jj) {
                    wf0[ktl][nt][jj] = (short)f2bf(cell_W[((size_t)(kb + jj)) * 1024 + n]);
                    wf1[ktl][nt][jj] = (short)f2bf(cell_W[((size_t)(512 + kb + jj)) * 1024 + n]);
                }
            }
    }
    const int hME = bi * 16 + (tid & 15);
    sCol[tid] = prev_s[(size_t)(tid >> 4) * 512 + hME];
    const float cb0h = cell_b[hME],        cb0t = cell_b[512 + hME];
    const float cb1h = cell_b[1024 + hME], cb1t = cell_b[1536 + hME];

    #pragma unroll 1
    for (int t = 0; t < T_; ++t) {
        // ================= phase A (batch role, b = bi) =================
        float sAv;
        if (t == 0) {
            sAv = prev_s[(size_t)bi * 512 + tid];
            __syncthreads();                     // part region free
            sA[tid] = sAv;
            __syncthreads();
        } else {
            const int* fp = &sF[tid >> 4];
            for (;;) {
                int v = ld_coh_u32(fp);
                if (v >= t) break;
                __builtin_amdgcn_s_sleep(1);
            }
            sAv = ld_coh_f32_nw(sG + ((size_t)(tid >> 4) * 32 + bi) * 16 + (tid & 15));
            __syncthreads();                     // overlaps the sG round-trip
            asm volatile("s_waitcnt vmcnt(0)" ::: "memory");
            sA[tid] = sAv;
            __syncthreads();
            // block 0 proved all sF >= t in its poll above -> publish the
            // aggregated epoch for the helper GEMM gate (fire and forget).
            if (bi == 0 && tid == 0)
                st_coh_u32(aggF, t);
        }

        // ---- scores (energy from LDS; 2-row ILP per wave) ----
        #pragma unroll 1
        for (int sp = 0; sp < 4; ++sp) {
            const int s0 = wv + sp * 16;
            const int s1 = s0 + 8;
            const bool has1 = (sp < 3) | (wv < 4);
            const float* e0 = &eL[s0][lane];
            const float* e1 = &eL[has1 ? s1 : s0][lane];
            float a0 = 0.f, a1 = 0.f;
            #pragma unroll
            for (int j = 0; j < 8; ++j) {
                float sv = sA[lane + j * 64];
                a0 = fmaf(e0[j * 64], sv, a0);
                a1 = fmaf(e1[j * 64], sv, a1);
            }
            #pragma unroll
            for (int off = 32; off; off >>= 1) {
                a0 += __shfl_xor(a0, off, 64);
                a1 += __shfl_xor(a1, off, 64);
            }
            if (lane == 0) {
                scoreL[s0] = a0;
                if (has1) scoreL[s1] = a1;
            }
        }
        __syncthreads();
        // ---- softmax (wave 0) ----
        if (wv == 0) {
            float v = (lane < S_) ? scoreL[lane] : -3.4e38f;
            float m = v;
            #pragma unroll
            for (int off = 32; off; off >>= 1) m = fmaxf(m, __shfl_xor(m, off, 64));
            float e = (lane < S_) ? __expf(v - m) : 0.f;
            float su = e;
            #pragma unroll
            for (int off = 32; off; off >>= 1) su += __shfl_xor(su, off, 64);
            if (lane < S_) alphaL[lane] = e / su;
        }
        __syncthreads();
        // ---- ctx (fp32 enc_h from L2, consume-as-you-go) + x0 out ----
        {
            float a = 0.f;
            const float* ep = enc_h + (size_t)bi * S_ * 1024 + tid;
            #pragma unroll 20
            for (int s = 0; s < S_; ++s) a = fmaf(alphaL[s], ep[(size_t)s * 1024], a);
            st_coh_f32(ctxG + (size_t)bi * 512 + tid, a);
            float x0 = a * sA[tid];
            unsigned short xh = f2bf(x0);
            unsigned short xl = f2bf(x0 - bflo((unsigned)xh));
            int kt = tid >> 5, lc2 = (tid >> 3) & 3, jj = tid & 7;
            int ch = (kt * 8 + lc2) * 32 + bi;
            st_coh_u16(xG0 + (size_t)ch * 8 + jj, xh);
            st_coh_u16(xG0 + (size_t)(ch + 128) * 8 + jj, xl);
        }
        gbar(cnt, 2 * t + 0, bi);
        // ================= phase B: two highway layers =================
        highway<0>(t, bi, tid, lane, wv, wf0, xG0, xG1, ctxG, sG, dec_b, pre,
                   cb0h, cb0t, part, sCol);
        gbar(cnt, 2 * t + 1, bi);
        highway<1>(t, bi, tid, lane, wv, wf1, xG1, xG1, ctxG, sG, dec_b, pre,
                   cb1h, cb1t, part, sCol);
        // s-ready + dec(t)-ready epoch flag (drained before store)
        asm volatile("s_waitcnt vmcnt(0)" ::: "memory");
        __syncthreads();
        if (tid == 0)
            st_coh_u32(&sF[bi], t + 1);
    }

    // final aggregated publish: block 0 waits for all sF >= T_ then sets
    // aggF = T_ so rbi=11 tiles (need = 48) can proceed.
    if (bi == 0) {
        if (tid < 64) {
            const int* fp2 = &sF[tid & 31];
            for (;;) {
                int v = ld_coh_u32(fp2);
                if (__all(v >= T_)) break;
                __builtin_amdgcn_s_sleep(1);
            }
        }
        __syncthreads();
        if (tid == 0)
            st_coh_u32(aggF, T_);
    }
}

// ---------------------------------------------------------------------------
extern "C" void kernel_launch(void* const* d_in, const int* in_sizes, int n_in,
                              void* d_out, int out_size, void* d_ws, size_t ws_size,
                              hipStream_t stream)
{
    const float* enc_h   = (const float*)d_in[0];
    const float* prev_s  = (const float*)d_in[1];
    const int*   target  = (const int*)  d_in[2];
    const float* embed_W = (const float*)d_in[3];
    const float* attn_W  = (const float*)d_in[4];
    const float* attn_b  = (const float*)d_in[5];
    const float* inp_W   = (const float*)d_in[6];
    const float* inp_b   = (const float*)d_in[7];
    const float* cell_W  = (const float*)d_in[8];
    const float* cell_b  = (const float*)d_in[9];
    const float* out_W   = (const float*)d_in[10];
    const float* out_b   = (const float*)d_in[11];
    float* out = (float*)d_out;

    float* ws = (float*)d_ws;
    float* energy = ws;                                       // 983040 f
    float* pre    = energy + (size_t)B_ * S_ * H_;            // 1572864 f
    float* ctxG   = pre + (size_t)T_ * B_ * 2 * H_;           // 16384 f
    float* sG     = ctxG + (size_t)B_ * H_;                   // 16384 f
    int*   cnt    = (int*)(sG + (size_t)B_ * H_);             // 4608 i (flags)
    unsigned short* dec_b = (unsigned short*)(cnt + 144 * 32);// 786432 u16 (block-major)
    unsigned short* xG0   = dec_b + (size_t)T_ * B_ * H_;     // 32768 u16 (frag-order)
    unsigned short* xG1   = xG0 + (size_t)2 * B_ * H_;        // 32768 u16 (frag-order)
    unsigned short* Wt    = xG1 + (size_t)2 * B_ * H_;        // NPAD*512 u16

    // 1. merged prologue (balanced): energy gemm (120) || pre gemm (96) ||
    //    flag zeroing (sc0sc1)
    gemm_pro<<<217, 256, 0, stream>>>(enc_h, attn_W, attn_b, energy,
                                      embed_W, inp_W, inp_b, pre, target, cnt);

    // 2. cooperative scan (blocks 0-31) + transpose AND overlapped output
    //    GEMM (blocks 32-255, gated on the aggregated epoch aggF, staggered)
    scan_tr<<<256, 512, 0, stream>>>(energy, enc_h, prev_s, pre, cell_W, cell_b,
                                     dec_b, out_W, Wt, ctxG, sG, xG0, xG1, cnt,
                                     out_b, out);
}

// Round 12
// 765.095 us; speedup vs baseline: 1.0865x; 1.0371x over previous
//
#include <hip/hip_runtime.h>
#include <hip/hip_bf16.h>
#include <math.h>

#define B_ 32
#define S_ 60
#define T_ 48
#define H_ 512
#define E_ 512
#define V_ 50257
#define NPAD 50432   // V_ padded up to multiple of 256
#define EPI_LD 260   // padded LDS stride for epilogue staging
#define NTILE ((NPAD / 256) * 12)   // 2364 output tiles

typedef __attribute__((ext_vector_type(8))) short bf16x8v;
typedef __attribute__((ext_vector_type(4))) float f32x4v;
typedef __attribute__((ext_vector_type(4))) float f32x4a __attribute__((aligned(4)));
typedef __attribute__((ext_vector_type(4))) unsigned int u32x4;

__device__ inline unsigned short f2bf(float f) {
    union { float f; unsigned u; } v; v.f = f;
    unsigned r = v.u + 0x7fffu + ((v.u >> 16) & 1u);   // round-to-nearest-even
    return (unsigned short)(r >> 16);
}
__device__ inline float bflo(unsigned u) { return __uint_as_float(u << 16); }

__device__ inline void gload_lds16(const void* g, void* l) {
    __builtin_amdgcn_global_load_lds(
        (const __attribute__((address_space(1))) unsigned int*)g,
        (__attribute__((address_space(3))) unsigned int*)l, 16, 0, 0);
}

// ---------------------------------------------------------------------------
// LLC-coherent (cache-bypassing) access helpers. sc0+sc1 => read/write at the
// coherence point. Rules (r4/r7 post-mortems):
//  - cells READ by other blocks in-flight (flags, sG, ctxG, xG*) are touched
//    ONLY via sc0sc1 on both sides;
//  - write-once buffers (Wt, dec_b) are WRITTEN sc0sc1 (write-through, no
//    dirty/cached L2 copies) and may be READ PLAIN after a ready-gate.
// ---------------------------------------------------------------------------
__device__ __forceinline__ float ld_coh_f32_nw(const float* p) {   // no wait
    float r;
    asm volatile("global_load_dword %0, %1, off sc0 sc1"
                 : "=v"(r) : "v"(p) : "memory");
    return r;
}
__device__ __forceinline__ void st_coh_f32(float* p, float v) {
    asm volatile("global_store_dword %0, %1, off sc0 sc1"
                 :: "v"(p), "v"(v) : "memory");
}
__device__ __forceinline__ void st_coh_u16(unsigned short* p, unsigned int v) {
    asm volatile("global_store_short %0, %1, off sc0 sc1"
                 :: "v"(p), "v"(v) : "memory");
}
__device__ __forceinline__ void st_coh_u32(int* p, int v) {
    asm volatile("global_store_dword %0, %1, off sc0 sc1"
                 :: "v"(p), "v"(v) : "memory");
}
__device__ __forceinline__ void st_coh_u64(unsigned long long* p, unsigned long long v) {
    asm volatile("global_store_dwordx2 %0, %1, off sc0 sc1"
                 :: "v"(p), "v"(v) : "memory");
}
__device__ __forceinline__ int ld_coh_u32(const int* p) {
    int r;
    asm volatile("global_load_dword %0, %1, off sc0 sc1\n\ts_waitcnt vmcnt(0)"
                 : "=v"(r) : "v"(p) : "memory");
    return r;
}
__device__ __forceinline__ u32x4 ld_cohx4(const void* p) {
    u32x4 r;
    asm volatile("global_load_dwordx4 %0, %1, off sc0 sc1"
                 : "=v"(r) : "v"(p) : "memory");
    return r;                     // caller must s_waitcnt vmcnt(0) before use
}

// ---------------------------------------------------------------------------
// 32-block device barrier, flag-array form.
// ---------------------------------------------------------------------------
__device__ __forceinline__ void gbar(int* flags, int idx, int bi) {
    asm volatile("s_waitcnt vmcnt(0)" ::: "memory");
    __syncthreads();
    if (threadIdx.x == 0)
        st_coh_u32(&flags[idx * 32 + bi], 1);
    if (threadIdx.x < 64) {
        const int* fp = &flags[idx * 32 + (threadIdx.x & 31)];
        for (;;) {
            int v = ld_coh_u32(fp);
            if (__all(v != 0)) break;
            __builtin_amdgcn_s_sleep(1);
        }
    }
    __syncthreads();
}

// ---------------------------------------------------------------------------
// fp32 tiled GEMM body; 256 threads, MR x 128 tile (MR=128 or 64), BK=32.
// BK=32 quarters the barrier count vs BK=8 (the r11 bottleneck: 128 iters x
// 2 barriers for K=1024). FMA order per output unchanged -> bit-identical.
// ---------------------------------------------------------------------------
template<int ACT, bool GATHER, int MR>
__device__ void gemm_body(const float* __restrict__ A, const float* __restrict__ Bm,
                          const float* __restrict__ bias, float* __restrict__ C,
                          int N, int K, int lda, const int* __restrict__ gidx,
                          int cb, int rb, float (*As)[128], float (*Bs)[128])
{
    const int tid = threadIdx.x;
    // A loader: MR rows x 32 k; 2 threads/row, 16 floats (4 x float4) each
    const int am = (MR == 128) ? (tid >> 1) : ((tid & 127) >> 1);
    const int ak = (tid & 1) * 16;
    const bool aact = (MR == 128) || (tid < 128);
    const int arow = rb + am;
    const float* Arow;
    if (GATHER) Arow = A + (size_t)gidx[arow] * lda;
    else        Arow = A + (size_t)arow * lda;

    // B loader: 32 rows x 128 cols; thread loads 16 consecutive floats
    const int bk = tid >> 3;                 // 0..31
    const int bn = (tid & 7) * 16;

    const int tx = tid & 15, ty = tid >> 4;
    float acc[MR / 16][8];
    #pragma unroll
    for (int i = 0; i < MR / 16; i++)
        #pragma unroll
        for (int j = 0; j < 8; j++) acc[i][j] = 0.f;

    for (int k0 = 0; k0 < K; k0 += 32) {
        float4 av[4], bv[4];
        if (aact) {
            #pragma unroll
            for (int j = 0; j < 4; ++j)
                av[j] = *(const float4*)(Arow + k0 + ak + 4 * j);
        }
        #pragma unroll
        for (int j = 0; j < 4; ++j)
            bv[j] = *(const float4*)(Bm + (size_t)(k0 + bk) * N + cb + bn + 4 * j);
        __syncthreads();
        if (aact) {
            #pragma unroll
            for (int j = 0; j < 4; ++j) {
                As[ak + 4 * j + 0][am] = av[j].x;
                As[ak + 4 * j + 1][am] = av[j].y;
                As[ak + 4 * j + 2][am] = av[j].z;
                As[ak + 4 * j + 3][am] = av[j].w;
            }
        }
        #pragma unroll
        for (int j = 0; j < 4; ++j)
            *(float4*)&Bs[bk][bn + 4 * j] = bv[j];
        __syncthreads();

        #pragma unroll 8
        for (int k = 0; k < 32; k++) {
            float a[MR / 16], b[8];
            if constexpr (MR == 128) {
                *(float4*)(a)     = *(const float4*)&As[k][ty * 4];
                *(float4*)(a + 4) = *(const float4*)&As[k][ty * 4 + 64];
            } else {
                *(float4*)(a)     = *(const float4*)&As[k][ty * 4];
            }
            *(float4*)(b)     = *(const float4*)&Bs[k][tx * 4];
            *(float4*)(b + 4) = *(const float4*)&Bs[k][tx * 4 + 64];
            #pragma unroll
            for (int i = 0; i < MR / 16; i++)
                #pragma unroll
                for (int j = 0; j < 8; j++)
                    acc[i][j] = fmaf(a[i], b[j], acc[i][j]);
        }
    }

    #pragma unroll
    for (int i = 0; i < MR / 16; i++) {
        int row;
        if constexpr (MR == 128)
            row = rb + ((i < 4) ? (ty * 4 + i) : (64 + ty * 4 + (i - 4)));
        else
            row = rb + ty * 4 + i;
        #pragma unroll
        for (int j = 0; j < 8; j++) {
            int col = cb + ((j < 4) ? (tx * 4 + j) : (64 + tx * 4 + (j - 4)));
            float v = acc[i][j] + bias[col];
            if (ACT == 1) v = tanhf(v);
            C[(size_t)row * N + col] = v;
        }
    }
}

// ---------------------------------------------------------------------------
// Merged prologue (balanced): blocks 0..119 = energy gemm (64x128 tiles,
// tanh), 120..215 = pre gemm (128x128, gathered), 216 = zero flags (sc0sc1).
//   rows 0..95   : gbar flags; row 100: sF; rows 101..107: hF; row 108: aggF
// ---------------------------------------------------------------------------
__global__ __launch_bounds__(256)
void gemm_pro(const float* __restrict__ enc_h, const float* __restrict__ attn_W,
              const float* __restrict__ attn_b, float* __restrict__ energy,
              const float* __restrict__ embed_W, const float* __restrict__ inp_W,
              const float* __restrict__ inp_b, float* __restrict__ pre,
              const int* __restrict__ target, int* __restrict__ cnt)
{
    __shared__ float As[32][128];
    __shared__ float Bs[32][128];
    const int bx = blockIdx.x;
    if (bx < 120) {
        // energy: M=1920 N=512 K=1024; 64x128 tiles, grid (4,30), 32 iters
        const int cb = (bx & 3) * 128, rb = (bx >> 2) * 64;
        gemm_body<1, false, 64>(enc_h, attn_W, attn_b, energy,
                                512, 1024, 1024, nullptr, cb, rb, As, Bs);
    } else if (bx < 216) {
        // pre: M=1536 N=1024 K=512; 128x128 tiles, grid (8,12), 16 iters
        const int b2 = bx - 120;
        const int cb = (b2 & 7) * 128, rb = (b2 >> 3) * 128;
        gemm_body<0, true, 128>(embed_W, inp_W, inp_b, pre,
                                1024, 512, 512, target, cb, rb, As, Bs);
    } else {
        for (int i = threadIdx.x; i < 144 * 32; i += 256)
            st_coh_u32(&cnt[i], 0);
    }
}

// ---------------------------------------------------------------------------
// Scan LDS (scan path) / transpose tiles + gemm smem (helper path).
// ---------------------------------------------------------------------------
union __align__(16) ScanSM {
    struct {
        float eL[S_][H_];        // 122880 B
        float part[8 * 32 * 36]; // 36864 B; overlay: sA[0..511] score[512..575] alpha[576..639]
        float sCol[512];         // 2048 B
    } s;
    float til[2 * 32 * 33];      // transpose tiles (helper, phase 1)
    char g[49152];               // gemm smem (helper, phase 2)
};

// ---------------------------------------------------------------------------
// x exchange buffers in MFMA-FRAGMENT order (direct LLC fragment loads).
// ---------------------------------------------------------------------------
template<int LI>
__device__ __forceinline__ void highway(
    int t, int bi, int tid, int lane, int wv,
    const bf16x8v (&wf)[2][2],
    const unsigned short* __restrict__ xsrc,
    unsigned short* __restrict__ xG1,
    const float* __restrict__ ctxG,
    float* __restrict__ sG,
    unsigned short* __restrict__ dec_b,
    const float* __restrict__ pre,
    float cbh, float cbt,
    float* part, float* sCol)
{
    const int l15 = lane & 15, lc = lane >> 4;
    const int b = tid >> 4, hi = tid & 15;
    const int h = bi * 16 + hi;

    // ---- issue cross-block ctx load + pre loads early (latency hidden) ----
    float cxv = 0.f, prh = 0.f, prt = 0.f;
    if (LI == 0) {
        cxv = ld_coh_f32_nw(ctxG + (size_t)b * 512 + h);
        const float* pr = pre + ((size_t)t * B_ + b) * 1024;
        prh = pr[h]; prt = pr[h + 512];
    }

    // ---- direct per-lane fragment loads from LLC (8 x 16B per lane) ----
    u32x4 xr[2][2][2];                       // [ktl][pl][mt]
    #pragma unroll
    for (int ktl = 0; ktl < 2; ++ktl)
        #pragma unroll
        for (int pl = 0; pl < 2; ++pl)
            #pragma unroll
            for (int mt = 0; mt < 2; ++mt) {
                int ch = (((wv * 2 + ktl) * 2 + pl) * 4 + lc) * 32 + mt * 16 + l15;
                xr[ktl][pl][mt] = ld_cohx4(xsrc + (size_t)ch * 8);
            }
    asm volatile("s_waitcnt vmcnt(0)" ::: "memory");
    __builtin_amdgcn_sched_barrier(0);

    // ---- MFMA: wave wv owns k-tiles {2wv, 2wv+1} ----
    f32x4v acc[2][2];
    #pragma unroll
    for (int mt = 0; mt < 2; ++mt)
        #pragma unroll
        for (int nt = 0; nt < 2; ++nt) acc[mt][nt] = (f32x4v)0.f;

    #pragma unroll
    for (int ktl = 0; ktl < 2; ++ktl)
        #pragma unroll
        for (int pl = 0; pl < 2; ++pl)
            #pragma unroll
            for (int mt = 0; mt < 2; ++mt) {
                bf16x8v xv = *(bf16x8v*)&xr[ktl][pl][mt];
                #pragma unroll
                for (int nt = 0; nt < 2; ++nt)
                    acc[mt][nt] = __builtin_amdgcn_mfma_f32_16x16x32_bf16(
                        wf[ktl][nt], xv, acc[mt][nt], 0, 0, 0);
            }

    #pragma unroll
    for (int mt = 0; mt < 2; ++mt)
        #pragma unroll
        for (int nt = 0; nt < 2; ++nt)
            *(f32x4v*)&part[(wv * 32 + mt * 16 + l15) * 36 + nt * 16 + lc * 4] = acc[mt][nt];
    __syncthreads();

    // ---- 8-way reduce + gates; thread tid -> (b = tid>>4, hi = tid&15) ----
    float rh = 0.f, rt = 0.f;
    #pragma unroll
    for (int w = 0; w < 8; ++w) {
        rh += part[(w * 32 + b) * 36 + hi];
        rt += part[(w * 32 + b) * 36 + 16 + hi];
    }
    float ph = rh + cbh, pt = rt + cbt;
    if (LI == 0) { ph += prh; pt += prt; }
    float hh = tanhf(ph);
    float tg = 1.f / (1.f + __expf(-pt));
    float sold = sCol[tid];
    float sn = hh * tg + sold * (1.f - tg);
    sCol[tid] = sn;
    if (LI == 0) {
        float x1 = sn * cxv;
        unsigned short xh = f2bf(x1);
        unsigned short xl = f2bf(x1 - bflo((unsigned)xh));
        int kt = h >> 5, lc2 = (h >> 3) & 3, jj = h & 7;
        int ch = (kt * 8 + lc2) * 32 + b;
        st_coh_u16(xG1 + (size_t)ch * 8 + jj, xh);
        st_coh_u16(xG1 + (size_t)(ch + 128) * 8 + jj, xl);
    } else {
        st_coh_f32(sG + ((size_t)bi * 32 + b) * 16 + hi, sn);
        st_coh_u16(dec_b + ((size_t)bi * 1536 + (size_t)t * B_ + b) * 16 + hi,
                   f2bf(sn));
    }
}

// ---------------------------------------------------------------------------
// Combined kernel:
//   blocks 0..31   = cooperative scan; block 0 additionally publishes the
//                    aggregated epoch aggF = t (proved by its phase-A poll).
//   blocks 32..255 = out_W transpose -> helper barrier -> overlapped output
//                    GEMM, tiles gated on aggF; gate-exit staggered.
// Helpers never block the scan; scan never waits on helpers -> no cycles.
// ---------------------------------------------------------------------------
__global__ __launch_bounds__(512, 2)
void scan_tr(const float* __restrict__ energy, const float* __restrict__ enc_h,
             const float* __restrict__ prev_s, const float* __restrict__ pre,
             const float* __restrict__ cell_W, const float* __restrict__ cell_b,
             unsigned short* __restrict__ dec_b,
             const float* __restrict__ outW, unsigned short* __restrict__ Wt,
             float* __restrict__ ctxG, float* __restrict__ sG,
             unsigned short* __restrict__ xG0, unsigned short* __restrict__ xG1,
             int* __restrict__ cnt,
             const float* __restrict__ out_b, float* __restrict__ out)
{
    __shared__ ScanSM sm;
    const int tid = threadIdx.x;
    int* aggF = cnt + 108 * 32;                  // aggregated scan epoch

    if (blockIdx.x >= B_) {
        // ============ helper phase 1: out_W -> Wt bf16 (sc0sc1 stores) ============
        const int hb = blockIdx.x - B_;          // 0..223
        const int g = tid >> 8;                  // 2 tile-groups per block
        const int tt0 = tid & 255;
        const int r = tt0 >> 3, c4 = (tt0 & 7) * 4;
        float* til = sm.til;                     // [2][32][33]
        #pragma unroll 1
        for (int j = 0; j < 57; ++j) {
            const int tt = hb * 2 + g + j * 448;
            const bool act = tt < (NPAD / 32) * 16;
            int n0 = 0, k0 = 0;
            if (act) {
                n0 = (tt >> 4) * 32;
                k0 = (tt & 15) * 32;
                #pragma unroll
                for (int jj = 0; jj < 4; ++jj) {
                    int n = n0 + c4 + jj;
                    til[(g * 32 + r) * 33 + c4 + jj] =
                        (n < V_) ? __builtin_nontemporal_load(&outW[(size_t)(k0 + r) * V_ + n]) : 0.f;
                }
            }
            __syncthreads();
            if (act) {
                const int n = n0 + r;
                unsigned lo = (unsigned)f2bf(til[(g * 32 + c4 + 0) * 33 + r])
                            | ((unsigned)f2bf(til[(g * 32 + c4 + 1) * 33 + r]) << 16);
                unsigned hi2 = (unsigned)f2bf(til[(g * 32 + c4 + 2) * 33 + r])
                             | ((unsigned)f2bf(til[(g * 32 + c4 + 3) * 33 + r]) << 16);
                unsigned long long ov = (unsigned long long)lo | ((unsigned long long)hi2 << 32);
                st_coh_u64((unsigned long long*)&Wt[(size_t)n * 512 + k0 + c4], ov);
            }
            __syncthreads();
        }

        // ============ helper barrier: all Wt tiles LLC-visible ============
        {
            int* hF = cnt + 101 * 32;            // 224 flags
            asm volatile("s_waitcnt vmcnt(0)" ::: "memory");
            __syncthreads();
            if (tid == 0) st_coh_u32(&hF[hb], 1);
            if (tid < 64) {
                for (;;) {
                    int ok = 1;
                    #pragma unroll
                    for (int q = 0; q < 4; ++q) {
                        int idx = (tid & 63) + q * 64;
                        int v = (idx < 224) ? ld_coh_u32(&hF[idx]) : 1;
                        ok &= (v != 0);
                    }
                    if (__all(ok)) break;
                    __builtin_amdgcn_s_sleep(16);
                }
            }
            __syncthreads();
        }

        // ============ helper phase 2: overlapped output GEMM ============
        {
            short* As_wt  = (short*)sm.g;               // 2 bufs x 8192 shorts
            short* Bs_dec = (short*)(sm.g + 32768);     // 2 bufs x 4096 shorts
            float* epi    = (float*)sm.g;               // epilogue staging
            const int lane = tid & 63, w = tid >> 6;
            const int wm = w >> 2, wn = w & 3;

#define STAGE_TILE(bix, kt, rb, cb) do {                                      \
            short* Ab_ = As_wt + (bix) * 8192;                                \
            short* Bb_ = Bs_dec + (bix) * 4096;                               \
            _Pragma("unroll")                                                 \
            for (int j_ = 0; j_ < 2; ++j_) {                                  \
                int rg_ = w * 2 + j_;                                         \
                int row_ = rg_ * 16 + (lane >> 2);                            \
                int kc_ = (lane & 3) ^ (row_ & 3);                            \
                gload_lds16(Wt + ((size_t)((cb) + row_) * 512 + (kt) * 32 + kc_ * 8), \
                            Ab_ + rg_ * 512);                                 \
            }                                                                 \
            {                                                                 \
                int row_ = w * 16 + (lane >> 2);                              \
                int kc_ = (lane & 3) ^ (row_ & 3);                            \
                gload_lds16(dec_b + (((size_t)((kt) * 2 + (kc_ >> 1)) * 1536 + ((rb) + row_)) * 16 \
                                     + (kc_ & 1) * 8),                        \
                            Bb_ + w * 512);                                   \
            }                                                                 \
        } while (0)

            #pragma unroll 1
            for (int i = hb; i < NTILE; i += 224) {
                const int rbi = i / 197;             // 0..11 (monotone per helper)
                const int rb  = rbi * 128;
                const int cb  = (i % 197) * 256;
                const int need = rbi * 4 + 4;        // dec rows final at aggF >= need

                if (tid < 64) {
                    // stagger pollers/stagers to de-burst LLC traffic
                    #pragma unroll 1
                    for (int z = 0; z < (hb & 31); ++z)
                        __builtin_amdgcn_s_sleep(8);
                    for (;;) {
                        int v = ld_coh_u32(aggF);
                        if (__all(v >= need)) break;
                        __builtin_amdgcn_s_sleep(64);
                    }
                }
                __syncthreads();

                f32x4v acc[4][4];
                #pragma unroll
                for (int mi = 0; mi < 4; ++mi)
                    #pragma unroll
                    for (int ni = 0; ni < 4; ++ni) acc[mi][ni] = (f32x4v)0.f;

                STAGE_TILE(0, 0, rb, cb);

                #pragma unroll 1
                for (int it = 0; it < 16; ++it) {
                    const int cur = it & 1;
                    __builtin_amdgcn_s_barrier();        // A: compute of it-1 done
                    asm volatile("" ::: "memory");
                    if (it < 15) {
                        STAGE_TILE(cur ^ 1, it + 1, rb, cb);
                        asm volatile("s_waitcnt vmcnt(3)" ::: "memory");
                    } else {
                        asm volatile("s_waitcnt vmcnt(0)" ::: "memory");
                    }
                    __builtin_amdgcn_s_barrier();        // B: it-tile loads landed
                    asm volatile("" ::: "memory");

                    const short* Ab = As_wt + cur * 8192;
                    const short* Bb = Bs_dec + cur * 4096;
                    bf16x8v af[4], bf[4];
                    const int lc = lane >> 4;            // k-chunk 0..3
                    #pragma unroll
                    for (int ni = 0; ni < 4; ++ni) {
                        int r_ = wn * 64 + ni * 16 + (lane & 15);
                        af[ni] = *(const bf16x8v*)&Ab[r_ * 32 + ((lc ^ (r_ & 3)) * 8)];
                    }
                    #pragma unroll
                    for (int mi = 0; mi < 4; ++mi) {
                        int r_ = wm * 64 + mi * 16 + (lane & 15);
                        bf[mi] = *(const bf16x8v*)&Bb[r_ * 32 + ((lc ^ (r_ & 3)) * 8)];
                    }
                    #pragma unroll
                    for (int mi = 0; mi < 4; ++mi)
                        #pragma unroll
                        for (int ni = 0; ni < 4; ++ni)
                            acc[mi][ni] = __builtin_amdgcn_mfma_f32_16x16x32_bf16(
                                af[ni], bf[mi], acc[mi][ni], 0, 0, 0);
                }

                // ---- coalesced epilogue via LDS ----
                const int c4e = (tid & 63) * 4;
                const bool fullcols = (cb + 256 <= V_);
                f32x4v bq = (f32x4v)0.f;
                if (fullcols) {
                    float4 t4 = *(const float4*)(out_b + cb + c4e);
                    bq[0] = t4.x; bq[1] = t4.y; bq[2] = t4.z; bq[3] = t4.w;
                }
                #pragma unroll
                for (int mi = 0; mi < 4; ++mi) {
                    __syncthreads();              // epi region free
                    #pragma unroll
                    for (int ni = 0; ni < 4; ++ni) {
                        const int er = wm * 16 + (lane & 15);
                        const int ec = wn * 64 + ni * 16 + (lane >> 4) * 4;
                        *(f32x4v*)&epi[er * EPI_LD + ec] = acc[mi][ni];
                    }
                    __syncthreads();
                    #pragma unroll
                    for (int j = 0; j < 4; ++j) {
                        const int rr = w + j * 8; // 0..31
                        const int orow = rb + (rr >> 4) * 64 + mi * 16 + (rr & 15);
                        f32x4v v = *(const f32x4v*)&epi[rr * EPI_LD + c4e];
                        if (fullcols) {
                            v += bq;
                            *(f32x4a*)(out + (size_t)orow * V_ + cb + c4e) = v;
                        } else {
                            #pragma unroll
                            for (int vv = 0; vv < 4; ++vv) {
                                const int col = cb + c4e + vv;
                                if (col < V_)
                                    out[(size_t)orow * V_ + col] = v[vv] + out_b[col];
                            }
                        }
                    }
                }
            }
#undef STAGE_TILE
        }
        return;
    }

    // ---------------- cooperative scan (r6 structure) ----------------
    const int bi = blockIdx.x;                   // batch (phase A) / col-slice (phase B)
    const int lane = tid & 63, wv = tid >> 6;    // 8 waves
    float (*eL)[H_] = sm.s.eL;
    float* part   = sm.s.part;
    float* sA     = part;                        // overlays (phase A only)
    float* scoreL = part + 512;
    float* alphaL = part + 576;
    float* sCol   = sm.s.sCol;
    int*   sF     = cnt + 100 * 32;              // s-epoch flags (32 ints)

    // ---- load energy slice into LDS once (float4) ----
    for (int i = tid; i < S_ * H_ / 4; i += 512) {
        int s = i >> 7, h4 = (i & 127) * 4;
        *(float4*)&eL[s][h4] = *(const float4*)&energy[((size_t)bi * S_ + s) * 512 + h4];
    }

    // ---- weight fragments: both layers, resident for the whole scan ----
    bf16x8v wf0[2][2], wf1[2][2];
    {
        const int l15 = lane & 15, lc = lane >> 4;
        #pragma unroll
        for (int ktl = 0; ktl < 2; ++ktl)
            #pragma unroll
            for (int nt = 0; nt < 2; ++nt) {
                const int kb = (wv * 2 + ktl) * 32 + lc * 8;
                const int n  = nt * 512 + bi * 16 + l15;
                #pragma unroll
                for (int jj = 0; jj < 8; ++jj) {
                    wf0[ktl][nt][jj] = (short)f2bf(cell_W[((size_t)(kb + jj)) * 1024 + n]);
                    wf1[ktl][nt][jj] = (short)f2bf(cell_W[((size_t)(512 + kb + jj)) * 1024 + n]);
                }
            }
    }
    const int hME = bi * 16 + (tid & 15);
    sCol[tid] = prev_s[(size_t)(tid >> 4) * 512 + hME];
    const float cb0h = cell_b[hME],        cb0t = cell_b[512 + hME];
    const float cb1h = cell_b[1024 + hME], cb1t = cell_b[1536 + hME];

    #pragma unroll 1
    for (int t = 0; t < T_; ++t) {
        // ================= phase A (batch role, b = bi) =================
        float sAv;
        if (t == 0) {
            sAv = prev_s[(size_t)bi * 512 + tid];
            __syncthreads();                     // part region free
            sA[tid] = sAv;
            __syncthreads();
        } else {
            const int* fp = &sF[tid >> 4];
            for (;;) {
                int v = ld_coh_u32(fp);
                if (v >= t) break;
                __builtin_amdgcn_s_sleep(1);
            }
            sAv = ld_coh_f32_nw(sG + ((size_t)(tid >> 4) * 32 + bi) * 16 + (tid & 15));
            __syncthreads();                     // overlaps the sG round-trip
            asm volatile("s_waitcnt vmcnt(0)" ::: "memory");
            sA[tid] = sAv;
            __syncthreads();
            // block 0 proved all sF >= t in its poll above -> publish the
            // aggregated epoch for the helper GEMM gate (fire and forget).
            if (bi == 0 && tid == 0)
                st_coh_u32(aggF, t);
        }

        // ---- scores (energy from LDS; 2-row ILP per wave) ----
        #pragma unroll 1
        for (int sp = 0; sp < 4; ++sp) {
            const int s0 = wv + sp * 16;
            const int s1 = s0 + 8;
            const bool has1 = (sp < 3) | (wv < 4);
            const float* e0 = &eL[s0][lane];
            const float* e1 = &eL[has1 ? s1 : s0][lane];
            float a0 = 0.f, a1 = 0.f;
            #pragma unroll
            for (int j = 0; j < 8; ++j) {
                float sv = sA[lane + j * 64];
                a0 = fmaf(e0[j * 64], sv, a0);
                a1 = fmaf(e1[j * 64], sv, a1);
            }
            #pragma unroll
            for (int off = 32; off; off >>= 1) {
                a0 += __shfl_xor(a0, off, 64);
                a1 += __shfl_xor(a1, off, 64);
            }
            if (lane == 0) {
                scoreL[s0] = a0;
                if (has1) scoreL[s1] = a1;
            }
        }
        __syncthreads();
        // ---- softmax (wave 0) ----
        if (wv == 0) {
            float v = (lane < S_) ? scoreL[lane] : -3.4e38f;
            float m = v;
            #pragma unroll
            for (int off = 32; off; off >>= 1) m = fmaxf(m, __shfl_xor(m, off, 64));
            float e = (lane < S_) ? __expf(v - m) : 0.f;
            float su = e;
            #pragma unroll
            for (int off = 32; off; off >>= 1) su += __shfl_xor(su, off, 64);
            if (lane < S_) alphaL[lane] = e / su;
        }
        __syncthreads();
        // ---- ctx (fp32 enc_h from L2, consume-as-you-go) + x0 out ----
        {
            float a = 0.f;
            const float* ep = enc_h + (size_t)bi * S_ * 1024 + tid;
            #pragma unroll 20
            for (int s = 0; s < S_; ++s) a = fmaf(alphaL[s], ep[(size_t)s * 1024], a);
            st_coh_f32(ctxG + (size_t)bi * 512 + tid, a);
            float x0 = a * sA[tid];
            unsigned short xh = f2bf(x0);
            unsigned short xl = f2bf(x0 - bflo((unsigned)xh));
            int kt = tid >> 5, lc2 = (tid >> 3) & 3, jj = tid & 7;
            int ch = (kt * 8 + lc2) * 32 + bi;
            st_coh_u16(xG0 + (size_t)ch * 8 + jj, xh);
            st_coh_u16(xG0 + (size_t)(ch + 128) * 8 + jj, xl);
        }
        gbar(cnt, 2 * t + 0, bi);
        // ================= phase B: two highway layers =================
        highway<0>(t, bi, tid, lane, wv, wf0, xG0, xG1, ctxG, sG, dec_b, pre,
                   cb0h, cb0t, part, sCol);
        gbar(cnt, 2 * t + 1, bi);
        highway<1>(t, bi, tid, lane, wv, wf1, xG1, xG1, ctxG, sG, dec_b, pre,
                   cb1h, cb1t, part, sCol);
        // s-ready + dec(t)-ready epoch flag (drained before store)
        asm volatile("s_waitcnt vmcnt(0)" ::: "memory");
        __syncthreads();
        if (tid == 0)
            st_coh_u32(&sF[bi], t + 1);
    }

    // final aggregated publish: block 0 waits for all sF >= T_ then sets
    // aggF = T_ so rbi=11 tiles (need = 48) can proceed.
    if (bi == 0) {
        if (tid < 64) {
            const int* fp2 = &sF[tid & 31];
            for (;;) {
                int v = ld_coh_u32(fp2);
                if (__all(v >= T_)) break;
                __builtin_amdgcn_s_sleep(1);
            }
        }
        __syncthreads();
        if (tid == 0)
            st_coh_u32(aggF, T_);
    }
}

// ---------------------------------------------------------------------------
extern "C" void kernel_launch(void* const* d_in, const int* in_sizes, int n_in,
                              void* d_out, int out_size, void* d_ws, size_t ws_size,
                              hipStream_t stream)
{
    const float* enc_h   = (const float*)d_in[0];
    const float* prev_s  = (const float*)d_in[1];
    const int*   target  = (const int*)  d_in[2];
    const float* embed_W = (const float*)d_in[3];
    const float* attn_W  = (const float*)d_in[4];
    const float* attn_b  = (const float*)d_in[5];
    const float* inp_W   = (const float*)d_in[6];
    const float* inp_b   = (const float*)d_in[7];
    const float* cell_W  = (const float*)d_in[8];
    const float* cell_b  = (const float*)d_in[9];
    const float* out_W   = (const float*)d_in[10];
    const float* out_b   = (const float*)d_in[11];
    float* out = (float*)d_out;

    float* ws = (float*)d_ws;
    float* energy = ws;                                       // 983040 f
    float* pre    = energy + (size_t)B_ * S_ * H_;            // 1572864 f
    float* ctxG   = pre + (size_t)T_ * B_ * 2 * H_;           // 16384 f
    float* sG     = ctxG + (size_t)B_ * H_;                   // 16384 f
    int*   cnt    = (int*)(sG + (size_t)B_ * H_);             // 4608 i (flags)
    unsigned short* dec_b = (unsigned short*)(cnt + 144 * 32);// 786432 u16 (block-major)
    unsigned short* xG0   = dec_b + (size_t)T_ * B_ * H_;     // 32768 u16 (frag-order)
    unsigned short* xG1   = xG0 + (size_t)2 * B_ * H_;        // 32768 u16 (frag-order)
    unsigned short* Wt    = xG1 + (size_t)2 * B_ * H_;        // NPAD*512 u16

    // 1. merged prologue (balanced, BK=32): energy gemm (120) || pre gemm
    //    (96) || flag zeroing (sc0sc1)
    gemm_pro<<<217, 256, 0, stream>>>(enc_h, attn_W, attn_b, energy,
                                      embed_W, inp_W, inp_b, pre, target, cnt);

    // 2. cooperative scan (blocks 0-31) + transpose AND overlapped output
    //    GEMM (blocks 32-255, gated on the aggregated epoch aggF, staggered)
    scan_tr<<<256, 512, 0, stream>>>(energy, enc_h, prev_s, pre, cell_W, cell_b,
                                     dec_b, out_W, Wt, ctxG, sG, xG0, xG1, cnt,
                                     out_b, out);
}

// Round 13
// 762.717 us; speedup vs baseline: 1.0899x; 1.0031x over previous
//
#include <hip/hip_runtime.h>
#include <hip/hip_bf16.h>
#include <math.h>

#define B_ 32
#define S_ 60
#define T_ 48
#define H_ 512
#define E_ 512
#define V_ 50257
#define NPAD 50432   // V_ padded up to multiple of 256
#define EPI_LD 260   // padded LDS stride for epilogue staging
#define NTILE ((NPAD / 256) * 12)   // 2364 output tiles

typedef __attribute__((ext_vector_type(8))) short bf16x8v;
typedef __attribute__((ext_vector_type(4))) float f32x4v;
typedef __attribute__((ext_vector_type(4))) float f32x4a __attribute__((aligned(4)));
typedef __attribute__((ext_vector_type(4))) unsigned int u32x4;

__device__ inline unsigned short f2bf(float f) {
    union { float f; unsigned u; } v; v.f = f;
    unsigned r = v.u + 0x7fffu + ((v.u >> 16) & 1u);   // round-to-nearest-even
    return (unsigned short)(r >> 16);
}
__device__ inline float bflo(unsigned u) { return __uint_as_float(u << 16); }

__device__ inline void gload_lds16(const void* g, void* l) {
    __builtin_amdgcn_global_load_lds(
        (const __attribute__((address_space(1))) unsigned int*)g,
        (__attribute__((address_space(3))) unsigned int*)l, 16, 0, 0);
}

// ---------------------------------------------------------------------------
// LLC-coherent (cache-bypassing) access helpers. sc0+sc1 => read/write at the
// coherence point. Rules (r4/r7 post-mortems):
//  - cells READ by other blocks in-flight (flags, sG, ctxG, xG*) are touched
//    ONLY via sc0sc1 on both sides;
//  - write-once buffers (Wt, dec_b) are WRITTEN sc0sc1 (write-through, no
//    dirty/cached L2 copies) and may be READ PLAIN after a ready-gate.
// ---------------------------------------------------------------------------
__device__ __forceinline__ float ld_coh_f32_nw(const float* p) {   // no wait
    float r;
    asm volatile("global_load_dword %0, %1, off sc0 sc1"
                 : "=v"(r) : "v"(p) : "memory");
    return r;
}
__device__ __forceinline__ void st_coh_f32(float* p, float v) {
    asm volatile("global_store_dword %0, %1, off sc0 sc1"
                 :: "v"(p), "v"(v) : "memory");
}
__device__ __forceinline__ void st_coh_u16(unsigned short* p, unsigned int v) {
    asm volatile("global_store_short %0, %1, off sc0 sc1"
                 :: "v"(p), "v"(v) : "memory");
}
__device__ __forceinline__ void st_coh_u32(int* p, int v) {
    asm volatile("global_store_dword %0, %1, off sc0 sc1"
                 :: "v"(p), "v"(v) : "memory");
}
__device__ __forceinline__ void st_coh_u64(unsigned long long* p, unsigned long long v) {
    asm volatile("global_store_dwordx2 %0, %1, off sc0 sc1"
                 :: "v"(p), "v"(v) : "memory");
}
__device__ __forceinline__ int ld_coh_u32(const int* p) {
    int r;
    asm volatile("global_load_dword %0, %1, off sc0 sc1\n\ts_waitcnt vmcnt(0)"
                 : "=v"(r) : "v"(p) : "memory");
    return r;
}
__device__ __forceinline__ u32x4 ld_cohx4(const void* p) {
    u32x4 r;
    asm volatile("global_load_dwordx4 %0, %1, off sc0 sc1"
                 : "=v"(r) : "v"(p) : "memory");
    return r;                     // caller must s_waitcnt vmcnt(0) before use
}

// ---------------------------------------------------------------------------
// 32-block device barrier, flag-array form.
// ---------------------------------------------------------------------------
__device__ __forceinline__ void gbar(int* flags, int idx, int bi) {
    asm volatile("s_waitcnt vmcnt(0)" ::: "memory");
    __syncthreads();
    if (threadIdx.x == 0)
        st_coh_u32(&flags[idx * 32 + bi], 1);
    if (threadIdx.x < 64) {
        const int* fp = &flags[idx * 32 + (threadIdx.x & 31)];
        for (;;) {
            int v = ld_coh_u32(fp);
            if (__all(v != 0)) break;
            __builtin_amdgcn_s_sleep(1);
        }
    }
    __syncthreads();
}

// ---------------------------------------------------------------------------
// fp32 tiled GEMM body; 256 threads, MR x 128 tile (MR=128 or 64), BK=32,
// REGISTER-PREFETCHED: next tile's global loads are issued between the
// LDS-write barrier and the compute, hiding L2/HBM latency under the FMA
// block (r12 post-mortem: loads were fully exposed). FMA order per output
// unchanged -> bit-identical results.
// ---------------------------------------------------------------------------
template<int ACT, bool GATHER, int MR>
__device__ void gemm_body(const float* __restrict__ A, const float* __restrict__ Bm,
                          const float* __restrict__ bias, float* __restrict__ C,
                          int N, int K, int lda, const int* __restrict__ gidx,
                          int cb, int rb, float (*As)[128], float (*Bs)[128])
{
    const int tid = threadIdx.x;
    // A loader: MR rows x 32 k; 2 threads/row, 16 floats (4 x float4) each
    const int am = (MR == 128) ? (tid >> 1) : ((tid & 127) >> 1);
    const int ak = (tid & 1) * 16;
    const bool aact = (MR == 128) || (tid < 128);
    const int arow = rb + am;
    const float* Arow;
    if (GATHER) Arow = A + (size_t)gidx[arow] * lda;
    else        Arow = A + (size_t)arow * lda;

    // B loader: 32 rows x 128 cols; thread loads 16 consecutive floats
    const int bk = tid >> 3;                 // 0..31
    const int bn = (tid & 7) * 16;

    const int tx = tid & 15, ty = tid >> 4;
    float acc[MR / 16][8];
    #pragma unroll
    for (int i = 0; i < MR / 16; i++)
        #pragma unroll
        for (int j = 0; j < 8; j++) acc[i][j] = 0.f;

    float4 av[4], bv[4];
    if (aact) {
        #pragma unroll
        for (int j = 0; j < 4; ++j)
            av[j] = *(const float4*)(Arow + ak + 4 * j);
    }
    #pragma unroll
    for (int j = 0; j < 4; ++j)
        bv[j] = *(const float4*)(Bm + (size_t)bk * N + cb + bn + 4 * j);

    for (int k0 = 0; k0 < K; k0 += 32) {
        __syncthreads();
        if (aact) {
            #pragma unroll
            for (int j = 0; j < 4; ++j) {
                As[ak + 4 * j + 0][am] = av[j].x;
                As[ak + 4 * j + 1][am] = av[j].y;
                As[ak + 4 * j + 2][am] = av[j].z;
                As[ak + 4 * j + 3][am] = av[j].w;
            }
        }
        #pragma unroll
        for (int j = 0; j < 4; ++j)
            *(float4*)&Bs[bk][bn + 4 * j] = bv[j];
        __syncthreads();

        // prefetch next K-tile into registers (overlaps the compute below)
        if (k0 + 32 < K) {
            if (aact) {
                #pragma unroll
                for (int j = 0; j < 4; ++j)
                    av[j] = *(const float4*)(Arow + k0 + 32 + ak + 4 * j);
            }
            #pragma unroll
            for (int j = 0; j < 4; ++j)
                bv[j] = *(const float4*)(Bm + (size_t)(k0 + 32 + bk) * N + cb + bn + 4 * j);
        }

        #pragma unroll 8
        for (int k = 0; k < 32; k++) {
            float a[MR / 16], b[8];
            if constexpr (MR == 128) {
                *(float4*)(a)     = *(const float4*)&As[k][ty * 4];
                *(float4*)(a + 4) = *(const float4*)&As[k][ty * 4 + 64];
            } else {
                *(float4*)(a)     = *(const float4*)&As[k][ty * 4];
            }
            *(float4*)(b)     = *(const float4*)&Bs[k][tx * 4];
            *(float4*)(b + 4) = *(const float4*)&Bs[k][tx * 4 + 64];
            #pragma unroll
            for (int i = 0; i < MR / 16; i++)
                #pragma unroll
                for (int j = 0; j < 8; j++)
                    acc[i][j] = fmaf(a[i], b[j], acc[i][j]);
        }
    }

    #pragma unroll
    for (int i = 0; i < MR / 16; i++) {
        int row;
        if constexpr (MR == 128)
            row = rb + ((i < 4) ? (ty * 4 + i) : (64 + ty * 4 + (i - 4)));
        else
            row = rb + ty * 4 + i;
        #pragma unroll
        for (int j = 0; j < 8; j++) {
            int col = cb + ((j < 4) ? (tx * 4 + j) : (64 + tx * 4 + (j - 4)));
            float v = acc[i][j] + bias[col];
            if (ACT == 1) v = tanhf(v);
            C[(size_t)row * N + col] = v;
        }
    }
}

// ---------------------------------------------------------------------------
// Merged prologue (balanced): blocks 0..119 = energy gemm (64x128 tiles,
// tanh), 120..215 = pre gemm (128x128, gathered). Flags zeroed by
// hipMemsetAsync (stream-ordered, graph-safe -- verified r10).
//   rows 0..95   : gbar flags; row 100: sF; rows 101..107: hF; row 108: aggF
// ---------------------------------------------------------------------------
__global__ __launch_bounds__(256)
void gemm_pro(const float* __restrict__ enc_h, const float* __restrict__ attn_W,
              const float* __restrict__ attn_b, float* __restrict__ energy,
              const float* __restrict__ embed_W, const float* __restrict__ inp_W,
              const float* __restrict__ inp_b, float* __restrict__ pre,
              const int* __restrict__ target)
{
    __shared__ float As[32][128];
    __shared__ float Bs[32][128];
    const int bx = blockIdx.x;
    if (bx < 120) {
        // energy: M=1920 N=512 K=1024; 64x128 tiles, grid (4,30), 32 iters
        const int cb = (bx & 3) * 128, rb = (bx >> 2) * 64;
        gemm_body<1, false, 64>(enc_h, attn_W, attn_b, energy,
                                512, 1024, 1024, nullptr, cb, rb, As, Bs);
    } else {
        // pre: M=1536 N=1024 K=512; 128x128 tiles, grid (8,12), 16 iters
        const int b2 = bx - 120;
        const int cb = (b2 & 7) * 128, rb = (b2 >> 3) * 128;
        gemm_body<0, true, 128>(embed_W, inp_W, inp_b, pre,
                                1024, 512, 512, target, cb, rb, As, Bs);
    }
}

// ---------------------------------------------------------------------------
// Scan LDS (scan path) / transpose tiles + gemm smem (helper path).
// ---------------------------------------------------------------------------
union __align__(16) ScanSM {
    struct {
        float eL[S_][H_];        // 122880 B
        float part[8 * 32 * 36]; // 36864 B; overlay: sA[0..511] score[512..575] alpha[576..639]
        float sCol[512];         // 2048 B
    } s;
    float til[2 * 32 * 33];      // transpose tiles (helper, phase 1)
    char g[49152];               // gemm smem (helper, phase 2)
};

// ---------------------------------------------------------------------------
// x exchange buffers in MFMA-FRAGMENT order (direct LLC fragment loads).
// ---------------------------------------------------------------------------
template<int LI>
__device__ __forceinline__ void highway(
    int t, int bi, int tid, int lane, int wv,
    const bf16x8v (&wf)[2][2],
    const unsigned short* __restrict__ xsrc,
    unsigned short* __restrict__ xG1,
    const float* __restrict__ ctxG,
    float* __restrict__ sG,
    unsigned short* __restrict__ dec_b,
    const float* __restrict__ pre,
    float cbh, float cbt,
    float* part, float* sCol)
{
    const int l15 = lane & 15, lc = lane >> 4;
    const int b = tid >> 4, hi = tid & 15;
    const int h = bi * 16 + hi;

    // ---- issue cross-block ctx load + pre loads early (latency hidden) ----
    float cxv = 0.f, prh = 0.f, prt = 0.f;
    if (LI == 0) {
        cxv = ld_coh_f32_nw(ctxG + (size_t)b * 512 + h);
        const float* pr = pre + ((size_t)t * B_ + b) * 1024;
        prh = pr[h]; prt = pr[h + 512];
    }

    // ---- direct per-lane fragment loads from LLC (8 x 16B per lane) ----
    u32x4 xr[2][2][2];                       // [ktl][pl][mt]
    #pragma unroll
    for (int ktl = 0; ktl < 2; ++ktl)
        #pragma unroll
        for (int pl = 0; pl < 2; ++pl)
            #pragma unroll
            for (int mt = 0; mt < 2; ++mt) {
                int ch = (((wv * 2 + ktl) * 2 + pl) * 4 + lc) * 32 + mt * 16 + l15;
                xr[ktl][pl][mt] = ld_cohx4(xsrc + (size_t)ch * 8);
            }
    asm volatile("s_waitcnt vmcnt(0)" ::: "memory");
    __builtin_amdgcn_sched_barrier(0);

    // ---- MFMA: wave wv owns k-tiles {2wv, 2wv+1} ----
    f32x4v acc[2][2];
    #pragma unroll
    for (int mt = 0; mt < 2; ++mt)
        #pragma unroll
        for (int nt = 0; nt < 2; ++nt) acc[mt][nt] = (f32x4v)0.f;

    #pragma unroll
    for (int ktl = 0; ktl < 2; ++ktl)
        #pragma unroll
        for (int pl = 0; pl < 2; ++pl)
            #pragma unroll
            for (int mt = 0; mt < 2; ++mt) {
                bf16x8v xv = *(bf16x8v*)&xr[ktl][pl][mt];
                #pragma unroll
                for (int nt = 0; nt < 2; ++nt)
                    acc[mt][nt] = __builtin_amdgcn_mfma_f32_16x16x32_bf16(
                        wf[ktl][nt], xv, acc[mt][nt], 0, 0, 0);
            }

    #pragma unroll
    for (int mt = 0; mt < 2; ++mt)
        #pragma unroll
        for (int nt = 0; nt < 2; ++nt)
            *(f32x4v*)&part[(wv * 32 + mt * 16 + l15) * 36 + nt * 16 + lc * 4] = acc[mt][nt];
    __syncthreads();

    // ---- 8-way reduce + gates; thread tid -> (b = tid>>4, hi = tid&15) ----
    float rh = 0.f, rt = 0.f;
    #pragma unroll
    for (int w = 0; w < 8; ++w) {
        rh += part[(w * 32 + b) * 36 + hi];
        rt += part[(w * 32 + b) * 36 + 16 + hi];
    }
    float ph = rh + cbh, pt = rt + cbt;
    if (LI == 0) { ph += prh; pt += prt; }
    float hh = tanhf(ph);
    float tg = 1.f / (1.f + __expf(-pt));
    float sold = sCol[tid];
    float sn = hh * tg + sold * (1.f - tg);
    sCol[tid] = sn;
    if (LI == 0) {
        float x1 = sn * cxv;
        unsigned short xh = f2bf(x1);
        unsigned short xl = f2bf(x1 - bflo((unsigned)xh));
        int kt = h >> 5, lc2 = (h >> 3) & 3, jj = h & 7;
        int ch = (kt * 8 + lc2) * 32 + b;
        st_coh_u16(xG1 + (size_t)ch * 8 + jj, xh);
        st_coh_u16(xG1 + (size_t)(ch + 128) * 8 + jj, xl);
    } else {
        st_coh_f32(sG + ((size_t)bi * 32 + b) * 16 + hi, sn);
        st_coh_u16(dec_b + ((size_t)bi * 1536 + (size_t)t * B_ + b) * 16 + hi,
                   f2bf(sn));
    }
}

// ---------------------------------------------------------------------------
// Combined kernel:
//   blocks 0..31   = cooperative scan; block 0 additionally publishes the
//                    aggregated epoch aggF = t (proved by its phase-A poll).
//   blocks 32..255 = out_W transpose -> helper barrier -> overlapped output
//                    GEMM, tiles gated on aggF; gate-exit staggered.
// Helpers never block the scan; scan never waits on helpers -> no cycles.
// ---------------------------------------------------------------------------
__global__ __launch_bounds__(512, 2)
void scan_tr(const float* __restrict__ energy, const float* __restrict__ enc_h,
             const float* __restrict__ prev_s, const float* __restrict__ pre,
             const float* __restrict__ cell_W, const float* __restrict__ cell_b,
             unsigned short* __restrict__ dec_b,
             const float* __restrict__ outW, unsigned short* __restrict__ Wt,
             float* __restrict__ ctxG, float* __restrict__ sG,
             unsigned short* __restrict__ xG0, unsigned short* __restrict__ xG1,
             int* __restrict__ cnt,
             const float* __restrict__ out_b, float* __restrict__ out)
{
    __shared__ ScanSM sm;
    const int tid = threadIdx.x;
    int* aggF = cnt + 108 * 32;                  // aggregated scan epoch

    if (blockIdx.x >= B_) {
        // ============ helper phase 1: out_W -> Wt bf16 (sc0sc1 stores) ============
        const int hb = blockIdx.x - B_;          // 0..223
        const int g = tid >> 8;                  // 2 tile-groups per block
        const int tt0 = tid & 255;
        const int r = tt0 >> 3, c4 = (tt0 & 7) * 4;
        float* til = sm.til;                     // [2][32][33]
        #pragma unroll 1
        for (int j = 0; j < 57; ++j) {
            const int tt = hb * 2 + g + j * 448;
            const bool act = tt < (NPAD / 32) * 16;
            int n0 = 0, k0 = 0;
            if (act) {
                n0 = (tt >> 4) * 32;
                k0 = (tt & 15) * 32;
                #pragma unroll
                for (int jj = 0; jj < 4; ++jj) {
                    int n = n0 + c4 + jj;
                    til[(g * 32 + r) * 33 + c4 + jj] =
                        (n < V_) ? __builtin_nontemporal_load(&outW[(size_t)(k0 + r) * V_ + n]) : 0.f;
                }
            }
            __syncthreads();
            if (act) {
                const int n = n0 + r;
                unsigned lo = (unsigned)f2bf(til[(g * 32 + c4 + 0) * 33 + r])
                            | ((unsigned)f2bf(til[(g * 32 + c4 + 1) * 33 + r]) << 16);
                unsigned hi2 = (unsigned)f2bf(til[(g * 32 + c4 + 2) * 33 + r])
                             | ((unsigned)f2bf(til[(g * 32 + c4 + 3) * 33 + r]) << 16);
                unsigned long long ov = (unsigned long long)lo | ((unsigned long long)hi2 << 32);
                st_coh_u64((unsigned long long*)&Wt[(size_t)n * 512 + k0 + c4], ov);
            }
            __syncthreads();
        }

        // ============ helper barrier: all Wt tiles LLC-visible ============
        {
            int* hF = cnt + 101 * 32;            // 224 flags
            asm volatile("s_waitcnt vmcnt(0)" ::: "memory");
            __syncthreads();
            if (tid == 0) st_coh_u32(&hF[hb], 1);
            if (tid < 64) {
                for (;;) {
                    int ok = 1;
                    #pragma unroll
                    for (int q = 0; q < 4; ++q) {
                        int idx = (tid & 63) + q * 64;
                        int v = (idx < 224) ? ld_coh_u32(&hF[idx]) : 1;
                        ok &= (v != 0);
                    }
                    if (__all(ok)) break;
                    __builtin_amdgcn_s_sleep(16);
                }
            }
            __syncthreads();
        }

        // ============ helper phase 2: overlapped output GEMM ============
        {
            short* As_wt  = (short*)sm.g;               // 2 bufs x 8192 shorts
            short* Bs_dec = (short*)(sm.g + 32768);     // 2 bufs x 4096 shorts
            float* epi    = (float*)sm.g;               // epilogue staging
            const int lane = tid & 63, w = tid >> 6;
            const int wm = w >> 2, wn = w & 3;

#define STAGE_TILE(bix, kt, rb, cb) do {                                      \
            short* Ab_ = As_wt + (bix) * 8192;                                \
            short* Bb_ = Bs_dec + (bix) * 4096;                               \
            _Pragma("unroll")                                                 \
            for (int j_ = 0; j_ < 2; ++j_) {                                  \
                int rg_ = w * 2 + j_;                                         \
                int row_ = rg_ * 16 + (lane >> 2);                            \
                int kc_ = (lane & 3) ^ (row_ & 3);                            \
                gload_lds16(Wt + ((size_t)((cb) + row_) * 512 + (kt) * 32 + kc_ * 8), \
                            Ab_ + rg_ * 512);                                 \
            }                                                                 \
            {                                                                 \
                int row_ = w * 16 + (lane >> 2);                              \
                int kc_ = (lane & 3) ^ (row_ & 3);                            \
                gload_lds16(dec_b + (((size_t)((kt) * 2 + (kc_ >> 1)) * 1536 + ((rb) + row_)) * 16 \
                                     + (kc_ & 1) * 8),                        \
                            Bb_ + w * 512);                                   \
            }                                                                 \
        } while (0)

            #pragma unroll 1
            for (int i = hb; i < NTILE; i += 224) {
                const int rbi = i / 197;             // 0..11 (monotone per helper)
                const int rb  = rbi * 128;
                const int cb  = (i % 197) * 256;
                const int need = rbi * 4 + 4;        // dec rows final at aggF >= need

                if (tid < 64) {
                    // stagger pollers/stagers to de-burst LLC traffic
                    #pragma unroll 1
                    for (int z = 0; z < (hb & 31); ++z)
                        __builtin_amdgcn_s_sleep(8);
                    for (;;) {
                        int v = ld_coh_u32(aggF);
                        if (__all(v >= need)) break;
                        __builtin_amdgcn_s_sleep(64);
                    }
                }
                __syncthreads();

                f32x4v acc[4][4];
                #pragma unroll
                for (int mi = 0; mi < 4; ++mi)
                    #pragma unroll
                    for (int ni = 0; ni < 4; ++ni) acc[mi][ni] = (f32x4v)0.f;

                STAGE_TILE(0, 0, rb, cb);

                #pragma unroll 1
                for (int it = 0; it < 16; ++it) {
                    const int cur = it & 1;
                    __builtin_amdgcn_s_barrier();        // A: compute of it-1 done
                    asm volatile("" ::: "memory");
                    if (it < 15) {
                        STAGE_TILE(cur ^ 1, it + 1, rb, cb);
                        asm volatile("s_waitcnt vmcnt(3)" ::: "memory");
                    } else {
                        asm volatile("s_waitcnt vmcnt(0)" ::: "memory");
                    }
                    __builtin_amdgcn_s_barrier();        // B: it-tile loads landed
                    asm volatile("" ::: "memory");

                    const short* Ab = As_wt + cur * 8192;
                    const short* Bb = Bs_dec + cur * 4096;
                    bf16x8v af[4], bf[4];
                    const int lc = lane >> 4;            // k-chunk 0..3
                    #pragma unroll
                    for (int ni = 0; ni < 4; ++ni) {
                        int r_ = wn * 64 + ni * 16 + (lane & 15);
                        af[ni] = *(const bf16x8v*)&Ab[r_ * 32 + ((lc ^ (r_ & 3)) * 8)];
                    }
                    #pragma unroll
                    for (int mi = 0; mi < 4; ++mi) {
                        int r_ = wm * 64 + mi * 16 + (lane & 15);
                        bf[mi] = *(const bf16x8v*)&Bb[r_ * 32 + ((lc ^ (r_ & 3)) * 8)];
                    }
                    #pragma unroll
                    for (int mi = 0; mi < 4; ++mi)
                        #pragma unroll
                        for (int ni = 0; ni < 4; ++ni)
                            acc[mi][ni] = __builtin_amdgcn_mfma_f32_16x16x32_bf16(
                                af[ni], bf[mi], acc[mi][ni], 0, 0, 0);
                }

                // ---- coalesced epilogue via LDS ----
                const int c4e = (tid & 63) * 4;
                const bool fullcols = (cb + 256 <= V_);
                f32x4v bq = (f32x4v)0.f;
                if (fullcols) {
                    float4 t4 = *(const float4*)(out_b + cb + c4e);
                    bq[0] = t4.x; bq[1] = t4.y; bq[2] = t4.z; bq[3] = t4.w;
                }
                #pragma unroll
                for (int mi = 0; mi < 4; ++mi) {
                    __syncthreads();              // epi region free
                    #pragma unroll
                    for (int ni = 0; ni < 4; ++ni) {
                        const int er = wm * 16 + (lane & 15);
                        const int ec = wn * 64 + ni * 16 + (lane >> 4) * 4;
                        *(f32x4v*)&epi[er * EPI_LD + ec] = acc[mi][ni];
                    }
                    __syncthreads();
                    #pragma unroll
                    for (int j = 0; j < 4; ++j) {
                        const int rr = w + j * 8; // 0..31
                        const int orow = rb + (rr >> 4) * 64 + mi * 16 + (rr & 15);
                        f32x4v v = *(const f32x4v*)&epi[rr * EPI_LD + c4e];
                        if (fullcols) {
                            v += bq;
                            *(f32x4a*)(out + (size_t)orow * V_ + cb + c4e) = v;
                        } else {
                            #pragma unroll
                            for (int vv = 0; vv < 4; ++vv) {
                                const int col = cb + c4e + vv;
                                if (col < V_)
                                    out[(size_t)orow * V_ + col] = v[vv] + out_b[col];
                            }
                        }
                    }
                }
            }
#undef STAGE_TILE
        }
        return;
    }

    // ---------------- cooperative scan (r6 structure) ----------------
    const int bi = blockIdx.x;                   // batch (phase A) / col-slice (phase B)
    const int lane = tid & 63, wv = tid >> 6;    // 8 waves
    float (*eL)[H_] = sm.s.eL;
    float* part   = sm.s.part;
    float* sA     = part;                        // overlays (phase A only)
    float* scoreL = part + 512;
    float* alphaL = part + 576;
    float* sCol   = sm.s.sCol;
    int*   sF     = cnt + 100 * 32;              // s-epoch flags (32 ints)

    // ---- load energy slice into LDS once (float4) ----
    for (int i = tid; i < S_ * H_ / 4; i += 512) {
        int s = i >> 7, h4 = (i & 127) * 4;
        *(float4*)&eL[s][h4] = *(const float4*)&energy[((size_t)bi * S_ + s) * 512 + h4];
    }

    // ---- weight fragments: both layers, resident for the whole scan ----
    bf16x8v wf0[2][2], wf1[2][2];
    {
        const int l15 = lane & 15, lc = lane >> 4;
        #pragma unroll
        for (int ktl = 0; ktl < 2; ++ktl)
            #pragma unroll
            for (int nt = 0; nt < 2; ++nt) {
                const int kb = (wv * 2 + ktl) * 32 + lc * 8;
                const int n  = nt * 512 + bi * 16 + l15;
                #pragma unroll
                for (int jj = 0; jj < 8; ++jj) {
                    wf0[ktl][nt][jj] = (short)f2bf(cell_W[((size_t)(kb + jj)) * 1024 + n]);
                    wf1[ktl][nt][jj] = (short)f2bf(cell_W[((size_t)(512 + kb + jj)) * 1024 + n]);
                }
            }
    }
    const int hME = bi * 16 + (tid & 15);
    sCol[tid] = prev_s[(size_t)(tid >> 4) * 512 + hME];
    const float cb0h = cell_b[hME],        cb0t = cell_b[512 + hME];
    const float cb1h = cell_b[1024 + hME], cb1t = cell_b[1536 + hME];

    #pragma unroll 1
    for (int t = 0; t < T_; ++t) {
        // ================= phase A (batch role, b = bi) =================
        float sAv;
        if (t == 0) {
            sAv = prev_s[(size_t)bi * 512 + tid];
            __syncthreads();                     // part region free
            sA[tid] = sAv;
            __syncthreads();
        } else {
            const int* fp = &sF[tid >> 4];
            for (;;) {
                int v = ld_coh_u32(fp);
                if (v >= t) break;
                __builtin_amdgcn_s_sleep(1);
            }
            sAv = ld_coh_f32_nw(sG + ((size_t)(tid >> 4) * 32 + bi) * 16 + (tid & 15));
            __syncthreads();                     // overlaps the sG round-trip
            asm volatile("s_waitcnt vmcnt(0)" ::: "memory");
            sA[tid] = sAv;
            __syncthreads();
            // block 0 proved all sF >= t in its poll above -> publish the
            // aggregated epoch for the helper GEMM gate (fire and forget).
            if (bi == 0 && tid == 0)
                st_coh_u32(aggF, t);
        }

        // ---- scores (energy from LDS; 2-row ILP per wave) ----
        #pragma unroll 1
        for (int sp = 0; sp < 4; ++sp) {
            const int s0 = wv + sp * 16;
            const int s1 = s0 + 8;
            const bool has1 = (sp < 3) | (wv < 4);
            const float* e0 = &eL[s0][lane];
            const float* e1 = &eL[has1 ? s1 : s0][lane];
            float a0 = 0.f, a1 = 0.f;
            #pragma unroll
            for (int j = 0; j < 8; ++j) {
                float sv = sA[lane + j * 64];
                a0 = fmaf(e0[j * 64], sv, a0);
                a1 = fmaf(e1[j * 64], sv, a1);
            }
            #pragma unroll
            for (int off = 32; off; off >>= 1) {
                a0 += __shfl_xor(a0, off, 64);
                a1 += __shfl_xor(a1, off, 64);
            }
            if (lane == 0) {
                scoreL[s0] = a0;
                if (has1) scoreL[s1] = a1;
            }
        }
        __syncthreads();
        // ---- softmax (wave 0) ----
        if (wv == 0) {
            float v = (lane < S_) ? scoreL[lane] : -3.4e38f;
            float m = v;
            #pragma unroll
            for (int off = 32; off; off >>= 1) m = fmaxf(m, __shfl_xor(m, off, 64));
            float e = (lane < S_) ? __expf(v - m) : 0.f;
            float su = e;
            #pragma unroll
            for (int off = 32; off; off >>= 1) su += __shfl_xor(su, off, 64);
            if (lane < S_) alphaL[lane] = e / su;
        }
        __syncthreads();
        // ---- ctx (fp32 enc_h from L2, consume-as-you-go) + x0 out ----
        {
            float a = 0.f;
            const float* ep = enc_h + (size_t)bi * S_ * 1024 + tid;
            #pragma unroll 20
            for (int s = 0; s < S_; ++s) a = fmaf(alphaL[s], ep[(size_t)s * 1024], a);
            st_coh_f32(ctxG + (size_t)bi * 512 + tid, a);
            float x0 = a * sA[tid];
            unsigned short xh = f2bf(x0);
            unsigned short xl = f2bf(x0 - bflo((unsigned)xh));
            int kt = tid >> 5, lc2 = (tid >> 3) & 3, jj = tid & 7;
            int ch = (kt * 8 + lc2) * 32 + bi;
            st_coh_u16(xG0 + (size_t)ch * 8 + jj, xh);
            st_coh_u16(xG0 + (size_t)(ch + 128) * 8 + jj, xl);
        }
        gbar(cnt, 2 * t + 0, bi);
        // ================= phase B: two highway layers =================
        highway<0>(t, bi, tid, lane, wv, wf0, xG0, xG1, ctxG, sG, dec_b, pre,
                   cb0h, cb0t, part, sCol);
        gbar(cnt, 2 * t + 1, bi);
        highway<1>(t, bi, tid, lane, wv, wf1, xG1, xG1, ctxG, sG, dec_b, pre,
                   cb1h, cb1t, part, sCol);
        // s-ready + dec(t)-ready epoch flag (drained before store)
        asm volatile("s_waitcnt vmcnt(0)" ::: "memory");
        __syncthreads();
        if (tid == 0)
            st_coh_u32(&sF[bi], t + 1);
    }

    // final aggregated publish: block 0 waits for all sF >= T_ then sets
    // aggF = T_ so rbi=11 tiles (need = 48) can proceed.
    if (bi == 0) {
        if (tid < 64) {
            const int* fp2 = &sF[tid & 31];
            for (;;) {
                int v = ld_coh_u32(fp2);
                if (__all(v >= T_)) break;
                __builtin_amdgcn_s_sleep(1);
            }
        }
        __syncthreads();
        if (tid == 0)
            st_coh_u32(aggF, T_);
    }
}

// ---------------------------------------------------------------------------
extern "C" void kernel_launch(void* const* d_in, const int* in_sizes, int n_in,
                              void* d_out, int out_size, void* d_ws, size_t ws_size,
                              hipStream_t stream)
{
    const float* enc_h   = (const float*)d_in[0];
    const float* prev_s  = (const float*)d_in[1];
    const int*   target  = (const int*)  d_in[2];
    const float* embed_W = (const float*)d_in[3];
    const float* attn_W  = (const float*)d_in[4];
    const float* attn_b  = (const float*)d_in[5];
    const float* inp_W   = (const float*)d_in[6];
    const float* inp_b   = (const float*)d_in[7];
    const float* cell_W  = (const float*)d_in[8];
    const float* cell_b  = (const float*)d_in[9];
    const float* out_W   = (const float*)d_in[10];
    const float* out_b   = (const float*)d_in[11];
    float* out = (float*)d_out;

    float* ws = (float*)d_ws;
    float* energy = ws;                                       // 983040 f
    float* pre    = energy + (size_t)B_ * S_ * H_;            // 1572864 f
    float* ctxG   = pre + (size_t)T_ * B_ * 2 * H_;           // 16384 f
    float* sG     = ctxG + (size_t)B_ * H_;                   // 16384 f
    int*   cnt    = (int*)(sG + (size_t)B_ * H_);             // 4608 i (flags)
    unsigned short* dec_b = (unsigned short*)(cnt + 144 * 32);// 786432 u16 (block-major)
    unsigned short* xG0   = dec_b + (size_t)T_ * B_ * H_;     // 32768 u16 (frag-order)
    unsigned short* xG1   = xG0 + (size_t)2 * B_ * H_;        // 32768 u16 (frag-order)
    unsigned short* Wt    = xG1 + (size_t)2 * B_ * H_;        // NPAD*512 u16

    // 0. zero all flags (stream-ordered, graph-safe -- r10 verified)
    hipMemsetAsync(cnt, 0, 144 * 32 * sizeof(int), stream);

    // 1. merged prologue (balanced, BK=32, register-prefetched):
    //    energy gemm (120) || pre gemm (96)
    gemm_pro<<<216, 256, 0, stream>>>(enc_h, attn_W, attn_b, energy,
                                      embed_W, inp_W, inp_b, pre, target);

    // 2. cooperative scan (blocks 0-31) + transpose AND overlapped output
    //    GEMM (blocks 32-255, gated on the aggregated epoch aggF, staggered)
    scan_tr<<<256, 512, 0, stream>>>(energy, enc_h, prev_s, pre, cell_W, cell_b,
                                     dec_b, out_W, Wt, ctxG, sG, xG0, xG1, cnt,
                                     out_b, out);
}